// Round 1
// 359.478 us; speedup vs baseline: 1.0011x; 1.0011x over previous
//
#include <hip/hip_runtime.h>
#include <math.h>

#define IN_F 128
#define HID 64
#define N_NODES 100000
#define N_EDGES 1000000
#define SCAN_BLOCKS 98   // ceil(N_NODES / 1024)

typedef __attribute__((ext_vector_type(8))) short bf16x8;
typedef __attribute__((ext_vector_type(4))) float f32x4;
typedef __attribute__((ext_vector_type(4))) unsigned short u16x4;

// round-to-nearest-even fp32 -> bf16 (inputs finite)
static __device__ __forceinline__ short f2bf(float f) {
    union { float f; unsigned u; } v; v.f = f;
    unsigned r = v.u + 0x7fffu + ((v.u >> 16) & 1u);
    return (short)(r >> 16);
}
static __device__ __forceinline__ unsigned short f2bfu(float f) {
    union { float f; unsigned u; } v; v.f = f;
    unsigned r = v.u + 0x7fffu + ((v.u >> 16) & 1u);
    return (unsigned short)(r >> 16);
}
static __device__ __forceinline__ float bf2f(unsigned short u) {
    union { unsigned u; float f; } v; v.u = ((unsigned)u) << 16; return v.f;
}

// ---------------------------------------------------------------------------
// Pack W ([128][64] fp32) into bf16 B-fragment layout:
//   entry (c*4+s)*64 + l  holds 8 bf16 = W[k][16c+n], k=32s+8q+j, l=16q+n
// ---------------------------------------------------------------------------
__global__ __launch_bounds__(256)
void pack_w_kernel(const float* __restrict__ W, short* __restrict__ Wpk)
{
    int i = blockIdx.x * 256 + threadIdx.x;   // 1024 entries
    if (i < 1024) {
        int l = i & 63, cs = i >> 6;
        int c = cs >> 2, s = cs & 3;
        int n = l & 15, q = l >> 4;
        short v[8];
        #pragma unroll
        for (int j = 0; j < 8; ++j)
            v[j] = f2bf(W[(32 * s + 8 * q + j) * HID + 16 * c + n]);
        *(bf16x8*)&Wpk[(size_t)i * 8] = *(const bf16x8*)v;
    }
}

// ---------------------------------------------------------------------------
// Fused 3x GEMM via bf16 MFMA, zero LDS / zero syncthreads.
// v2: 4 m-tiles (64 rows) per wave, B-fragments register-resident (64 VGPR),
//     double-buffered A prefetch (statically unrolled -> no scratch).
//   A-frag: lane m=l&15, k=8*quad+j  (global fp32 -> inline bf16)
//   B-frag: from pre-packed Wpk (coalesced 16B loads, L2-hot, loaded ONCE)
//   C/D:    col=l&15, row=4*quad+reg  [m89/m91 verified]
// which==0 -> H0 fp32 + p0 ; which==1/2 -> H bf16 + q1/q2
// ---------------------------------------------------------------------------
__global__ __launch_bounds__(256, 2)
void lin_att_mfma(const float* __restrict__ feat0, const float* __restrict__ feat1,
                  const float* __restrict__ feat2,
                  const short* __restrict__ Wpk, const float* __restrict__ b_feat,
                  const float* __restrict__ W_att,
                  float* __restrict__ H0,
                  unsigned short* __restrict__ H1b, unsigned short* __restrict__ H2b,
                  float* __restrict__ p0, float* __restrict__ q1, float* __restrict__ q2)
{
    const int which = blockIdx.y;
    const float* feat = (which == 0) ? feat0 : (which == 1) ? feat1 : feat2;
    float* sOut = (which == 0) ? p0 : (which == 1) ? q1 : q2;
    unsigned short* Hb = (which == 1) ? H1b : H2b;

    const int t  = threadIdx.x;
    const int wv = t >> 6;
    const int l  = t & 63;
    const int n  = l & 15;
    const int q  = l >> 4;
    const int waveBase = blockIdx.x * 256 + wv * 64;   // 64 rows per wave

    // B-fragments: whole packed W held per-wave (64 VGPR), reused for 4 m-tiles
    bf16x8 Bf[4][4];
    #pragma unroll
    for (int c = 0; c < 4; ++c)
        #pragma unroll
        for (int s = 0; s < 4; ++s)
            Bf[c][s] = *(const bf16x8*)&Wpk[((c * 4 + s) * 64 + l) * 8];

    // per-column scalars, loaded once
    float bias_c[4], att_c[4];
    #pragma unroll
    for (int c = 0; c < 4; ++c) {
        int col = 16 * c + n;
        bias_c[c] = b_feat[col];
        float a0 = W_att[col], a1 = W_att[HID + col];
        att_c[c] = (which == 0) ? (a0 + a1 * (1.0f / 3.0f)) : (a1 * (1.0f / 3.0f));
    }

    float4 X[2][8];   // double-buffered A staging (all indices static after unroll)

    // prologue: load m-tile 0
    {
        int gr = waveBase + n;
        int lr = (gr < N_NODES) ? gr : (N_NODES - 1);
        const float* ap = &feat[(size_t)lr * IN_F + 8 * q];
        #pragma unroll
        for (int s = 0; s < 4; ++s) {
            X[0][2 * s]     = *(const float4*)(ap + 32 * s);
            X[0][2 * s + 1] = *(const float4*)(ap + 32 * s + 4);
        }
    }

    #pragma unroll
    for (int mt = 0; mt < 4; ++mt) {
        const int buf = mt & 1;

        // prefetch next tile's A while this tile converts/MFMAs
        if (mt < 3) {
            int gr = waveBase + (mt + 1) * 16 + n;
            int lr = (gr < N_NODES) ? gr : (N_NODES - 1);
            const float* ap = &feat[(size_t)lr * IN_F + 8 * q];
            #pragma unroll
            for (int s = 0; s < 4; ++s) {
                X[buf ^ 1][2 * s]     = *(const float4*)(ap + 32 * s);
                X[buf ^ 1][2 * s + 1] = *(const float4*)(ap + 32 * s + 4);
            }
        }

        f32x4 acc[4];
        #pragma unroll
        for (int c = 0; c < 4; ++c) {
            float bv = bias_c[c];
            acc[c][0] = bv; acc[c][1] = bv; acc[c][2] = bv; acc[c][3] = bv;
        }

        #pragma unroll
        for (int s = 0; s < 4; ++s) {
            float4 x0 = X[buf][2 * s];
            float4 x1 = X[buf][2 * s + 1];
            bf16x8 a;
            a[0] = f2bf(x0.x); a[1] = f2bf(x0.y); a[2] = f2bf(x0.z); a[3] = f2bf(x0.w);
            a[4] = f2bf(x1.x); a[5] = f2bf(x1.y); a[6] = f2bf(x1.z); a[7] = f2bf(x1.w);
            #pragma unroll
            for (int c = 0; c < 4; ++c)
                acc[c] = __builtin_amdgcn_mfma_f32_16x16x32_bf16(a, Bf[c][s], acc[c], 0, 0, 0);
        }

        // epilogue: store H (+ fused attention scalar in fp32)
        const int rowBase = waveBase + mt * 16;
        float part[4] = {0.f, 0.f, 0.f, 0.f};
        #pragma unroll
        for (int c = 0; c < 4; ++c) {
            int col = 16 * c + n;
            #pragma unroll
            for (int r = 0; r < 4; ++r) {
                int row = rowBase + 4 * q + r;
                if (row < N_NODES) {
                    if (which == 0) H0[(size_t)row * HID + col] = acc[c][r];
                    else            Hb[(size_t)row * HID + col] = f2bfu(acc[c][r]);
                }
                part[r] = fmaf(acc[c][r], att_c[c], part[r]);
            }
        }
        #pragma unroll
        for (int r = 0; r < 4; ++r) {
            float p = part[r];
            p += __shfl_xor(p, 1, 64);
            p += __shfl_xor(p, 2, 64);
            p += __shfl_xor(p, 4, 64);
            p += __shfl_xor(p, 8, 64);
            int row = rowBase + 4 * q + r;
            if (n == 0 && row < N_NODES) sOut[row] = p;
        }
    }
}

// ---------------------------------------------------------------------------
// CSR build
// ---------------------------------------------------------------------------
__global__ __launch_bounds__(256)
void hist_kernel(const int* __restrict__ e0a, int* __restrict__ counts)
{
    int i = blockIdx.x * 256 + threadIdx.x;
    if (i < N_EDGES / 4) {
        int4 e = ((const int4*)e0a)[i];
        atomicAdd(&counts[e.x], 1);
        atomicAdd(&counts[e.y], 1);
        atomicAdd(&counts[e.z], 1);
        atomicAdd(&counts[e.w], 1);
    }
}

__global__ __launch_bounds__(256)
void scan1_kernel(const int* __restrict__ counts, int* __restrict__ offsets,
                  int* __restrict__ blockSums)
{
    __shared__ int s[256];
    int t = threadIdx.x;
    int base = blockIdx.x * 1024 + t * 4;
    int c0 = (base + 0 < N_NODES) ? counts[base + 0] : 0;
    int c1 = (base + 1 < N_NODES) ? counts[base + 1] : 0;
    int c2 = (base + 2 < N_NODES) ? counts[base + 2] : 0;
    int c3 = (base + 3 < N_NODES) ? counts[base + 3] : 0;
    int tsum = c0 + c1 + c2 + c3;
    s[t] = tsum;
    __syncthreads();
    for (int off = 1; off < 256; off <<= 1) {
        int v = (t >= off) ? s[t - off] : 0;
        __syncthreads();
        s[t] += v;
        __syncthreads();
    }
    int excl = s[t] - tsum;
    if (base + 0 < N_NODES) offsets[base + 0] = excl;
    if (base + 1 < N_NODES) offsets[base + 1] = excl + c0;
    if (base + 2 < N_NODES) offsets[base + 2] = excl + c0 + c1;
    if (base + 3 < N_NODES) offsets[base + 3] = excl + c0 + c1 + c2;
    if (t == 255) blockSums[blockIdx.x] = s[255];
}

__global__ __launch_bounds__(128)
void scan2_kernel(int* __restrict__ blockSums)
{
    __shared__ int s[128];
    int t = threadIdx.x;
    int v = (t < SCAN_BLOCKS) ? blockSums[t] : 0;
    s[t] = v;
    __syncthreads();
    for (int off = 1; off < 128; off <<= 1) {
        int u = (t >= off) ? s[t - off] : 0;
        __syncthreads();
        s[t] += u;
        __syncthreads();
    }
    if (t < SCAN_BLOCKS) blockSums[t] = s[t] - v;   // exclusive
}

__global__ __launch_bounds__(256)
void scan3_kernel(int* __restrict__ offsets, int* __restrict__ cursor,
                  const int* __restrict__ blockSums)
{
    int t = threadIdx.x;
    int base = blockIdx.x * 1024 + t * 4;
    int add = blockSums[blockIdx.x];
    #pragma unroll
    for (int k = 0; k < 4; ++k) {
        int i = base + k;
        if (i < N_NODES) {
            int v = offsets[i] + add;
            offsets[i] = v;
            cursor[i] = v;
        }
    }
}

// scatter: edge score + packed record (e1, e2, ex, pad) at dest-sorted pos
__global__ __launch_bounds__(256)
void scatter_kernel(const int* __restrict__ e0a, const int* __restrict__ e1a,
                    const int* __restrict__ e2a,
                    const float* __restrict__ p0, const float* __restrict__ q1,
                    const float* __restrict__ q2, const float* __restrict__ b_att,
                    int* __restrict__ cursor, float4* __restrict__ rec)
{
    int i = blockIdx.x * 256 + threadIdx.x;
    if (i < N_EDGES) {
        int e0 = e0a[i], e1 = e1a[i], e2 = e2a[i];
        float x = p0[e0] + q1[e1] + q2[e2] + b_att[0];
        // tanh in [-1,1] => exp(tanh) safe; softmax shift-invariance makes
        // skipping the segment-max exact.
        float ex = __expf(tanhf(x));
        int pos = atomicAdd(&cursor[e0], 1);
        rec[pos] = make_float4(__int_as_float(e1), __int_as_float(e2), ex, 0.0f);
    }
}

// ---------------------------------------------------------------------------
// Aggregate (CSR, fused): 16 lanes/node, zero atomics, bf16 gathers.
// out[n] = bias + H0[n]/3 + (1/(3*sum_ex)) * sum_e ex_e*(H1[e1]+H2[e2])
// ---------------------------------------------------------------------------
__global__ __launch_bounds__(256)
void aggregate_csr_kernel(const int* __restrict__ offsets, const int* __restrict__ counts,
                          const float4* __restrict__ rec,
                          const float* __restrict__ H0,
                          const unsigned short* __restrict__ H1b,
                          const unsigned short* __restrict__ H2b,
                          const float* __restrict__ bias,
                          float* __restrict__ out)
{
    int gid  = blockIdx.x * 256 + threadIdx.x;
    int node = gid >> 4;
    int sub  = gid & 15;
    if (node >= N_NODES) return;

    int start = offsets[node];
    int cnt   = counts[node];

    float denom = 0.0f;
    float ax = 0.0f, ay = 0.0f, az = 0.0f, aw = 0.0f;
    for (int j = 0; j < cnt; ++j) {
        float4 r = rec[start + j];                 // broadcast across 16 lanes
        int e1 = __float_as_int(r.x);
        int e2 = __float_as_int(r.y);
        float w = r.z;
        u16x4 h1 = *(const u16x4*)&H1b[(size_t)e1 * HID + 4 * sub];
        u16x4 h2 = *(const u16x4*)&H2b[(size_t)e2 * HID + 4 * sub];
        denom += w;
        ax = fmaf(w, bf2f(h1.x) + bf2f(h2.x), ax);
        ay = fmaf(w, bf2f(h1.y) + bf2f(h2.y), ay);
        az = fmaf(w, bf2f(h1.z) + bf2f(h2.z), az);
        aw = fmaf(w, bf2f(h1.w) + bf2f(h2.w), aw);
    }

    float4 h0 = *(const float4*)&H0[(size_t)node * HID + 4 * sub];
    float4 bv = *(const float4*)&bias[4 * sub];
    float third = (cnt > 0) ? (1.0f / 3.0f) : 0.0f;
    float inv   = (cnt > 0) ? 1.0f / (3.0f * denom) : 0.0f;

    float4 o;
    o.x = bv.x + third * h0.x + inv * ax;
    o.y = bv.y + third * h0.y + inv * ay;
    o.z = bv.z + third * h0.z + inv * az;
    o.w = bv.w + third * h0.w + inv * aw;
    *(float4*)&out[(size_t)node * HID + 4 * sub] = o;
}

// ---------------------------------------------------------------------------
extern "C" void kernel_launch(void* const* d_in, const int* in_sizes, int n_in,
                              void* d_out, int out_size, void* d_ws, size_t ws_size,
                              hipStream_t stream)
{
    const float* feat0  = (const float*)d_in[0];
    const float* feat1  = (const float*)d_in[1];
    const float* feat2  = (const float*)d_in[2];
    const int*   edge0  = (const int*)d_in[3];
    const int*   edge1  = (const int*)d_in[4];
    const int*   edge2  = (const int*)d_in[5];
    const float* W_feat = (const float*)d_in[6];
    const float* b_feat = (const float*)d_in[7];
    const float* W_att  = (const float*)d_in[8];
    const float* b_att  = (const float*)d_in[9];
    const float* bias   = (const float*)d_in[10];
    float* out = (float*)d_out;

    // workspace layout (16B-aligned chunks first)
    float4* rec  = (float4*)d_ws;                          // 1M float4 = 16 MB
    short*  Wpk  = (short*)(rec + N_EDGES);                // 8192 shorts (16 KB)
    float*  H0   = (float*)(Wpk + 8192);                   // 6.4M floats
    unsigned short* H1b = (unsigned short*)(H0 + (size_t)N_NODES * HID); // 6.4M
    unsigned short* H2b = H1b + (size_t)N_NODES * HID;                   // 6.4M
    float*  p0   = (float*)(H2b + (size_t)N_NODES * HID);
    float*  q1   = p0 + N_NODES;
    float*  q2   = q1 + N_NODES;
    int* counts    = (int*)(q2 + N_NODES);
    int* offsets   = counts + N_NODES;
    int* cursor    = offsets + N_NODES;
    int* blockSums = cursor + N_NODES;                     // 128
    // total ~72 MB

    (void)hipMemsetAsync(counts, 0, N_NODES * sizeof(int), stream);

    dim3 blk(256);
    pack_w_kernel<<<4, blk, 0, stream>>>(W_feat, Wpk);

    dim3 gemmGrid((N_NODES + 255) / 256, 3);
    lin_att_mfma<<<gemmGrid, blk, 0, stream>>>(feat0, feat1, feat2,
                                               Wpk, b_feat, W_att,
                                               H0, H1b, H2b, p0, q1, q2);

    hist_kernel<<<(N_EDGES / 4 + 255) / 256, blk, 0, stream>>>(edge0, counts);
    scan1_kernel<<<SCAN_BLOCKS, blk, 0, stream>>>(counts, offsets, blockSums);
    scan2_kernel<<<1, 128, 0, stream>>>(blockSums);
    scan3_kernel<<<SCAN_BLOCKS, blk, 0, stream>>>(offsets, cursor, blockSums);

    scatter_kernel<<<(N_EDGES + 255) / 256, blk, 0, stream>>>(
        edge0, edge1, edge2, p0, q1, q2, b_att, cursor, rec);

    aggregate_csr_kernel<<<((size_t)N_NODES * 16 + 255) / 256, blk, 0, stream>>>(
        offsets, counts, rec, H0, H1b, H2b, bias, out);
}

// Round 3
// 358.579 us; speedup vs baseline: 1.0036x; 1.0025x over previous
//
#include <hip/hip_runtime.h>
#include <math.h>

#define IN_F 128
#define HID 64
#define N_NODES 100000
#define N_EDGES 1000000
#define SCAN_BLOCKS 98   // ceil(N_NODES / 1024)

typedef __attribute__((ext_vector_type(8))) short bf16x8;
typedef __attribute__((ext_vector_type(4))) float f32x4;
typedef __attribute__((ext_vector_type(4))) unsigned short u16x4;

// round-to-nearest-even fp32 -> bf16 (inputs finite)
static __device__ __forceinline__ short f2bf(float f) {
    union { float f; unsigned u; } v; v.f = f;
    unsigned r = v.u + 0x7fffu + ((v.u >> 16) & 1u);
    return (short)(r >> 16);
}
static __device__ __forceinline__ unsigned short f2bfu(float f) {
    union { float f; unsigned u; } v; v.f = f;
    unsigned r = v.u + 0x7fffu + ((v.u >> 16) & 1u);
    return (unsigned short)(r >> 16);
}
static __device__ __forceinline__ float bf2f(unsigned short u) {
    union { unsigned u; float f; } v; v.u = ((unsigned)u) << 16; return v.f;
}

// ---------------------------------------------------------------------------
// Pack W ([128][64] fp32) into bf16 B-fragment layout:
//   entry (c*4+s)*64 + l  holds 8 bf16 = W[k][16c+n], k=32s+8q+j, l=16q+n
// ---------------------------------------------------------------------------
__global__ __launch_bounds__(256)
void pack_w_kernel(const float* __restrict__ W, short* __restrict__ Wpk)
{
    int i = blockIdx.x * 256 + threadIdx.x;   // 1024 entries
    if (i < 1024) {
        int l = i & 63, cs = i >> 6;
        int c = cs >> 2, s = cs & 3;
        int n = l & 15, q = l >> 4;
        short v[8];
        #pragma unroll
        for (int j = 0; j < 8; ++j)
            v[j] = f2bf(W[(32 * s + 8 * q + j) * HID + 16 * c + n]);
        *(bf16x8*)&Wpk[(size_t)i * 8] = *(const bf16x8*)v;
    }
}

// ---------------------------------------------------------------------------
// Fused 3x GEMM via bf16 MFMA, zero LDS / zero syncthreads.
// v4: 1 tile/wave (v1 shape, max wave count). All 24 loads (8 A + 16 B) are
//     issued up front, then a sched_barrier(0) fences the schedule so the
//     compiler CANNOT re-sink them into the MFMA loop (v1's failure mode:
//     VGPR=48 => 4 serial load->wait->mfma round trips). One wait, 16 MFMAs.
//   A-frag: lane m=l&15, k=8*quad+j  (global fp32 -> inline bf16)
//   B-frag: from pre-packed Wpk (coalesced 16B loads, L2-hot)
//   C/D:    col=l&15, row=4*quad+reg  [m89/m91 verified]
// which==0 -> H0 fp32 + p0 ; which==1/2 -> H bf16 + q1/q2
// ---------------------------------------------------------------------------
__global__ __launch_bounds__(256)
void lin_att_mfma(const float* __restrict__ feat0, const float* __restrict__ feat1,
                  const float* __restrict__ feat2,
                  const short* __restrict__ Wpk, const float* __restrict__ b_feat,
                  const float* __restrict__ W_att,
                  float* __restrict__ H0,
                  unsigned short* __restrict__ H1b, unsigned short* __restrict__ H2b,
                  float* __restrict__ p0, float* __restrict__ q1, float* __restrict__ q2)
{
    const int which = blockIdx.y;
    const float* feat = (which == 0) ? feat0 : (which == 1) ? feat1 : feat2;
    float* sOut = (which == 0) ? p0 : (which == 1) ? q1 : q2;
    unsigned short* Hb = (which == 1) ? H1b : H2b;

    const int t  = threadIdx.x;
    const int wv = t >> 6;
    const int l  = t & 63;
    const int n  = l & 15;
    const int q  = l >> 4;
    const int rowBase = blockIdx.x * 64 + wv * 16;

    const int gRow = rowBase + n;
    const int lr = (gRow < N_NODES) ? gRow : (N_NODES - 1);   // clamp loads

    // --- issue ALL A loads (8 x dwordx4, HBM/L3) ---
    float4 X[8];
    {
        const float* ap = &feat[(size_t)lr * IN_F + 8 * q];
        #pragma unroll
        for (int s = 0; s < 4; ++s) {
            X[2 * s]     = *(const float4*)(ap + 32 * s);
            X[2 * s + 1] = *(const float4*)(ap + 32 * s + 4);
        }
    }

    // --- issue ALL B loads (16 x dwordx4, L2 broadcast) ---
    bf16x8 Bf[4][4];
    #pragma unroll
    for (int c = 0; c < 4; ++c)
        #pragma unroll
        for (int s = 0; s < 4; ++s)
            Bf[c][s] = *(const bf16x8*)&Wpk[((c * 4 + s) * 64 + l) * 8];

    // --- schedule fence: nothing crosses. All 24 loads stay issued above
    //     (in flight together); converts/MFMAs stay below. Forces ~100 VGPR
    //     live across ONE wait instead of 4 serial round trips. ---
    __builtin_amdgcn_sched_barrier(0);

    f32x4 acc[4];
    #pragma unroll
    for (int c = 0; c < 4; ++c) {
        float bv = b_feat[16 * c + n];
        acc[c][0] = bv; acc[c][1] = bv; acc[c][2] = bv; acc[c][3] = bv;
    }

    #pragma unroll
    for (int s = 0; s < 4; ++s) {
        float4 x0 = X[2 * s];
        float4 x1 = X[2 * s + 1];
        bf16x8 a;
        a[0] = f2bf(x0.x); a[1] = f2bf(x0.y); a[2] = f2bf(x0.z); a[3] = f2bf(x0.w);
        a[4] = f2bf(x1.x); a[5] = f2bf(x1.y); a[6] = f2bf(x1.z); a[7] = f2bf(x1.w);
        #pragma unroll
        for (int c = 0; c < 4; ++c)
            acc[c] = __builtin_amdgcn_mfma_f32_16x16x32_bf16(a, Bf[c][s], acc[c], 0, 0, 0);
    }

    // epilogue: store H (+ fused attention scalar in fp32)
    float part[4] = {0.f, 0.f, 0.f, 0.f};
    #pragma unroll
    for (int c = 0; c < 4; ++c) {
        int col = 16 * c + n;
        float a0 = W_att[col], a1 = W_att[HID + col];
        float ae = (which == 0) ? (a0 + a1 * (1.0f / 3.0f)) : (a1 * (1.0f / 3.0f));
        #pragma unroll
        for (int r = 0; r < 4; ++r) {
            int row = rowBase + 4 * q + r;
            if (row < N_NODES) {
                if (which == 0) H0[(size_t)row * HID + col] = acc[c][r];
                else            Hb[(size_t)row * HID + col] = f2bfu(acc[c][r]);
            }
            part[r] = fmaf(acc[c][r], ae, part[r]);
        }
    }
    #pragma unroll
    for (int r = 0; r < 4; ++r) {
        float p = part[r];
        p += __shfl_xor(p, 1, 64);
        p += __shfl_xor(p, 2, 64);
        p += __shfl_xor(p, 4, 64);
        p += __shfl_xor(p, 8, 64);
        int row = rowBase + 4 * q + r;
        if (n == 0 && row < N_NODES) sOut[row] = p;
    }
}

// ---------------------------------------------------------------------------
// CSR build
// ---------------------------------------------------------------------------
__global__ __launch_bounds__(256)
void hist_kernel(const int* __restrict__ e0a, int* __restrict__ counts)
{
    int i = blockIdx.x * 256 + threadIdx.x;
    if (i < N_EDGES / 4) {
        int4 e = ((const int4*)e0a)[i];
        atomicAdd(&counts[e.x], 1);
        atomicAdd(&counts[e.y], 1);
        atomicAdd(&counts[e.z], 1);
        atomicAdd(&counts[e.w], 1);
    }
}

__global__ __launch_bounds__(256)
void scan1_kernel(const int* __restrict__ counts, int* __restrict__ offsets,
                  int* __restrict__ blockSums)
{
    __shared__ int s[256];
    int t = threadIdx.x;
    int base = blockIdx.x * 1024 + t * 4;
    int c0 = (base + 0 < N_NODES) ? counts[base + 0] : 0;
    int c1 = (base + 1 < N_NODES) ? counts[base + 1] : 0;
    int c2 = (base + 2 < N_NODES) ? counts[base + 2] : 0;
    int c3 = (base + 3 < N_NODES) ? counts[base + 3] : 0;
    int tsum = c0 + c1 + c2 + c3;
    s[t] = tsum;
    __syncthreads();
    for (int off = 1; off < 256; off <<= 1) {
        int v = (t >= off) ? s[t - off] : 0;
        __syncthreads();
        s[t] += v;
        __syncthreads();
    }
    int excl = s[t] - tsum;
    if (base + 0 < N_NODES) offsets[base + 0] = excl;
    if (base + 1 < N_NODES) offsets[base + 1] = excl + c0;
    if (base + 2 < N_NODES) offsets[base + 2] = excl + c0 + c1;
    if (base + 3 < N_NODES) offsets[base + 3] = excl + c0 + c1 + c2;
    if (t == 255) blockSums[blockIdx.x] = s[255];
}

__global__ __launch_bounds__(128)
void scan2_kernel(int* __restrict__ blockSums)
{
    __shared__ int s[128];
    int t = threadIdx.x;
    int v = (t < SCAN_BLOCKS) ? blockSums[t] : 0;
    s[t] = v;
    __syncthreads();
    for (int off = 1; off < 128; off <<= 1) {
        int u = (t >= off) ? s[t - off] : 0;
        __syncthreads();
        s[t] += u;
        __syncthreads();
    }
    if (t < SCAN_BLOCKS) blockSums[t] = s[t] - v;   // exclusive
}

__global__ __launch_bounds__(256)
void scan3_kernel(int* __restrict__ offsets, int* __restrict__ cursor,
                  const int* __restrict__ blockSums)
{
    int t = threadIdx.x;
    int base = blockIdx.x * 1024 + t * 4;
    int add = blockSums[blockIdx.x];
    #pragma unroll
    for (int k = 0; k < 4; ++k) {
        int i = base + k;
        if (i < N_NODES) {
            int v = offsets[i] + add;
            offsets[i] = v;
            cursor[i] = v;
        }
    }
}

// scatter: edge score + packed record (e1, e2, ex, pad) at dest-sorted pos
// v3: 4 edges/thread via int4 -> 4x gathers/atomics in flight per thread
__global__ __launch_bounds__(256)
void scatter_kernel(const int* __restrict__ e0a, const int* __restrict__ e1a,
                    const int* __restrict__ e2a,
                    const float* __restrict__ p0, const float* __restrict__ q1,
                    const float* __restrict__ q2, const float* __restrict__ b_att,
                    int* __restrict__ cursor, float4* __restrict__ rec)
{
    int i = blockIdx.x * 256 + threadIdx.x;
    if (i < N_EDGES / 4) {
        int4 e0v = ((const int4*)e0a)[i];
        int4 e1v = ((const int4*)e1a)[i];
        int4 e2v = ((const int4*)e2a)[i];
        float ba = b_att[0];

        // four independent gather chains, issued together
        float x0 = p0[e0v.x] + q1[e1v.x] + q2[e2v.x] + ba;
        float x1 = p0[e0v.y] + q1[e1v.y] + q2[e2v.y] + ba;
        float x2 = p0[e0v.z] + q1[e1v.z] + q2[e2v.z] + ba;
        float x3 = p0[e0v.w] + q1[e1v.w] + q2[e2v.w] + ba;
        // tanh in [-1,1] => exp(tanh) safe; softmax shift-invariance makes
        // skipping the segment-max exact.
        float ex0 = __expf(tanhf(x0));
        float ex1 = __expf(tanhf(x1));
        float ex2 = __expf(tanhf(x2));
        float ex3 = __expf(tanhf(x3));

        int pos0 = atomicAdd(&cursor[e0v.x], 1);
        int pos1 = atomicAdd(&cursor[e0v.y], 1);
        int pos2 = atomicAdd(&cursor[e0v.z], 1);
        int pos3 = atomicAdd(&cursor[e0v.w], 1);
        rec[pos0] = make_float4(__int_as_float(e1v.x), __int_as_float(e2v.x), ex0, 0.0f);
        rec[pos1] = make_float4(__int_as_float(e1v.y), __int_as_float(e2v.y), ex1, 0.0f);
        rec[pos2] = make_float4(__int_as_float(e1v.z), __int_as_float(e2v.z), ex2, 0.0f);
        rec[pos3] = make_float4(__int_as_float(e1v.w), __int_as_float(e2v.w), ex3, 0.0f);
    }
}

// ---------------------------------------------------------------------------
// Aggregate (CSR, fused): 16 lanes/node, zero atomics, bf16 gathers.
// v3: j-loop unrolled by 2 -> 2x gather MLP (loads of both iterations
//     are independent and issue together).
// out[n] = bias + H0[n]/3 + (1/(3*sum_ex)) * sum_e ex_e*(H1[e1]+H2[e2])
// ---------------------------------------------------------------------------
__global__ __launch_bounds__(256)
void aggregate_csr_kernel(const int* __restrict__ offsets, const int* __restrict__ counts,
                          const float4* __restrict__ rec,
                          const float* __restrict__ H0,
                          const unsigned short* __restrict__ H1b,
                          const unsigned short* __restrict__ H2b,
                          const float* __restrict__ bias,
                          float* __restrict__ out)
{
    int gid  = blockIdx.x * 256 + threadIdx.x;
    int node = gid >> 4;
    int sub  = gid & 15;
    if (node >= N_NODES) return;

    int start = offsets[node];
    int cnt   = counts[node];

    float denom = 0.0f;
    float ax = 0.0f, ay = 0.0f, az = 0.0f, aw = 0.0f;

    int j = 0;
    for (; j + 2 <= cnt; j += 2) {
        float4 r0 = rec[start + j];
        float4 r1 = rec[start + j + 1];
        int e1_0 = __float_as_int(r0.x), e2_0 = __float_as_int(r0.y);
        int e1_1 = __float_as_int(r1.x), e2_1 = __float_as_int(r1.y);
        u16x4 h1_0 = *(const u16x4*)&H1b[(size_t)e1_0 * HID + 4 * sub];
        u16x4 h2_0 = *(const u16x4*)&H2b[(size_t)e2_0 * HID + 4 * sub];
        u16x4 h1_1 = *(const u16x4*)&H1b[(size_t)e1_1 * HID + 4 * sub];
        u16x4 h2_1 = *(const u16x4*)&H2b[(size_t)e2_1 * HID + 4 * sub];
        float w0 = r0.z, w1 = r1.z;
        denom += w0 + w1;
        ax = fmaf(w0, bf2f(h1_0.x) + bf2f(h2_0.x), ax);
        ay = fmaf(w0, bf2f(h1_0.y) + bf2f(h2_0.y), ay);
        az = fmaf(w0, bf2f(h1_0.z) + bf2f(h2_0.z), az);
        aw = fmaf(w0, bf2f(h1_0.w) + bf2f(h2_0.w), aw);
        ax = fmaf(w1, bf2f(h1_1.x) + bf2f(h2_1.x), ax);
        ay = fmaf(w1, bf2f(h1_1.y) + bf2f(h2_1.y), ay);
        az = fmaf(w1, bf2f(h1_1.z) + bf2f(h2_1.z), az);
        aw = fmaf(w1, bf2f(h1_1.w) + bf2f(h2_1.w), aw);
    }
    if (j < cnt) {
        float4 r = rec[start + j];
        int e1 = __float_as_int(r.x);
        int e2 = __float_as_int(r.y);
        float w = r.z;
        u16x4 h1 = *(const u16x4*)&H1b[(size_t)e1 * HID + 4 * sub];
        u16x4 h2 = *(const u16x4*)&H2b[(size_t)e2 * HID + 4 * sub];
        denom += w;
        ax = fmaf(w, bf2f(h1.x) + bf2f(h2.x), ax);
        ay = fmaf(w, bf2f(h1.y) + bf2f(h2.y), ay);
        az = fmaf(w, bf2f(h1.z) + bf2f(h2.z), az);
        aw = fmaf(w, bf2f(h1.w) + bf2f(h2.w), aw);
    }

    float4 h0 = *(const float4*)&H0[(size_t)node * HID + 4 * sub];
    float4 bv = *(const float4*)&bias[4 * sub];
    float third = (cnt > 0) ? (1.0f / 3.0f) : 0.0f;
    float inv   = (cnt > 0) ? 1.0f / (3.0f * denom) : 0.0f;

    float4 o;
    o.x = bv.x + third * h0.x + inv * ax;
    o.y = bv.y + third * h0.y + inv * ay;
    o.z = bv.z + third * h0.z + inv * az;
    o.w = bv.w + third * h0.w + inv * aw;
    *(float4*)&out[(size_t)node * HID + 4 * sub] = o;
}

// ---------------------------------------------------------------------------
extern "C" void kernel_launch(void* const* d_in, const int* in_sizes, int n_in,
                              void* d_out, int out_size, void* d_ws, size_t ws_size,
                              hipStream_t stream)
{
    const float* feat0  = (const float*)d_in[0];
    const float* feat1  = (const float*)d_in[1];
    const float* feat2  = (const float*)d_in[2];
    const int*   edge0  = (const int*)d_in[3];
    const int*   edge1  = (const int*)d_in[4];
    const int*   edge2  = (const int*)d_in[5];
    const float* W_feat = (const float*)d_in[6];
    const float* b_feat = (const float*)d_in[7];
    const float* W_att  = (const float*)d_in[8];
    const float* b_att  = (const float*)d_in[9];
    const float* bias   = (const float*)d_in[10];
    float* out = (float*)d_out;

    // workspace layout (16B-aligned chunks first)
    float4* rec  = (float4*)d_ws;                          // 1M float4 = 16 MB
    short*  Wpk  = (short*)(rec + N_EDGES);                // 8192 shorts (16 KB)
    float*  H0   = (float*)(Wpk + 8192);                   // 6.4M floats
    unsigned short* H1b = (unsigned short*)(H0 + (size_t)N_NODES * HID); // 6.4M
    unsigned short* H2b = H1b + (size_t)N_NODES * HID;                   // 6.4M
    float*  p0   = (float*)(H2b + (size_t)N_NODES * HID);
    float*  q1   = p0 + N_NODES;
    float*  q2   = q1 + N_NODES;
    int* counts    = (int*)(q2 + N_NODES);
    int* offsets   = counts + N_NODES;
    int* cursor    = offsets + N_NODES;
    int* blockSums = cursor + N_NODES;                     // 128
    // total ~72 MB

    (void)hipMemsetAsync(counts, 0, N_NODES * sizeof(int), stream);

    dim3 blk(256);
    pack_w_kernel<<<4, blk, 0, stream>>>(W_feat, Wpk);

    dim3 gemmGrid((N_NODES + 63) / 64, 3);
    lin_att_mfma<<<gemmGrid, blk, 0, stream>>>(feat0, feat1, feat2,
                                               Wpk, b_feat, W_att,
                                               H0, H1b, H2b, p0, q1, q2);

    hist_kernel<<<(N_EDGES / 4 + 255) / 256, blk, 0, stream>>>(edge0, counts);
    scan1_kernel<<<SCAN_BLOCKS, blk, 0, stream>>>(counts, offsets, blockSums);
    scan2_kernel<<<1, 128, 0, stream>>>(blockSums);
    scan3_kernel<<<SCAN_BLOCKS, blk, 0, stream>>>(offsets, cursor, blockSums);

    scatter_kernel<<<(N_EDGES / 4 + 255) / 256, blk, 0, stream>>>(
        edge0, edge1, edge2, p0, q1, q2, b_att, cursor, rec);

    aggregate_csr_kernel<<<((size_t)N_NODES * 16 + 255) / 256, blk, 0, stream>>>(
        offsets, counts, rec, H0, H1b, H2b, bias, out);
}

// Round 4
// 351.560 us; speedup vs baseline: 1.0236x; 1.0200x over previous
//
#include <hip/hip_runtime.h>
#include <math.h>

#define IN_F 128
#define HID 64
#define N_NODES 100000
#define N_EDGES 1000000
#define SCAN_BLOCKS 98   // ceil(N_NODES / 1024)
#define GEMM_BLOCKS 1563 // ceil(N_NODES / 64)

typedef __attribute__((ext_vector_type(8))) short bf16x8;
typedef __attribute__((ext_vector_type(4))) float f32x4;
typedef __attribute__((ext_vector_type(4))) unsigned short u16x4;

// round-to-nearest-even fp32 -> bf16 (inputs finite)
static __device__ __forceinline__ short f2bf(float f) {
    union { float f; unsigned u; } v; v.f = f;
    unsigned r = v.u + 0x7fffu + ((v.u >> 16) & 1u);
    return (short)(r >> 16);
}
static __device__ __forceinline__ unsigned short f2bfu(float f) {
    union { float f; unsigned u; } v; v.f = f;
    unsigned r = v.u + 0x7fffu + ((v.u >> 16) & 1u);
    return (unsigned short)(r >> 16);
}
static __device__ __forceinline__ float bf2f(unsigned short u) {
    union { unsigned u; float f; } v; v.u = ((unsigned)u) << 16; return v.f;
}

// ---------------------------------------------------------------------------
// K1: pack_w (blocks 0..3) ∥ hist (blocks 4..980) — independent work fused
// so the 1M histogram atomics hide under nothing-in-particular and cost one
// launch instead of two.
// ---------------------------------------------------------------------------
__global__ __launch_bounds__(256)
void k1_pack_hist(const float* __restrict__ W, short* __restrict__ Wpk,
                  const int* __restrict__ e0a, int* __restrict__ counts)
{
    int bx = blockIdx.x;
    if (bx < 4) {
        int i = bx * 256 + threadIdx.x;   // 1024 entries
        if (i < 1024) {
            int l = i & 63, cs = i >> 6;
            int c = cs >> 2, s = cs & 3;
            int n = l & 15, q = l >> 4;
            short v[8];
            #pragma unroll
            for (int j = 0; j < 8; ++j)
                v[j] = f2bf(W[(32 * s + 8 * q + j) * HID + 16 * c + n]);
            *(bf16x8*)&Wpk[(size_t)i * 8] = *(const bf16x8*)v;
        }
    } else {
        int i = (bx - 4) * 256 + threadIdx.x;
        if (i < N_EDGES / 4) {
            int4 e = ((const int4*)e0a)[i];
            atomicAdd(&counts[e.x], 1);
            atomicAdd(&counts[e.y], 1);
            atomicAdd(&counts[e.z], 1);
            atomicAdd(&counts[e.w], 1);
        }
    }
}

// ---------------------------------------------------------------------------
// K2: scan1 (blocks 0..97) ∥ lin_att (blocks 98..98+4688) — scan1 reads
// counts (done in K1), lin_att reads Wpk (done in K1). Both latency-bound,
// disjoint outputs; overlapping them removes scan1 from the serial sum.
//
// lin_att: fused 3x GEMM via bf16 MFMA, zero LDS / zero syncthreads.
//   All 24 loads (8 A + 16 B) issued up front + sched_barrier(0) fence so
//   the compiler cannot re-sink them (v1 failure: VGPR=48 => 4 serial
//   load->wait->mfma round trips). One wait, 16 back-to-back MFMAs.
//   A-frag: lane m=l&15, k=8*quad+j  (global fp32 -> inline bf16)
//   B-frag: from pre-packed Wpk (coalesced 16B loads, L2-hot)
//   C/D:    col=l&15, row=4*quad+reg  [m89/m91 verified]
// which==0 -> H0 fp32 + p0 ; which==1/2 -> H bf16 + q1/q2
// ---------------------------------------------------------------------------
__global__ __launch_bounds__(256)
void k2_lin_scan1(const float* __restrict__ feat0, const float* __restrict__ feat1,
                  const float* __restrict__ feat2,
                  const short* __restrict__ Wpk, const float* __restrict__ b_feat,
                  const float* __restrict__ W_att,
                  float* __restrict__ H0,
                  unsigned short* __restrict__ H1b, unsigned short* __restrict__ H2b,
                  float* __restrict__ p0, float* __restrict__ q1, float* __restrict__ q2,
                  const int* __restrict__ counts, int* __restrict__ offsets,
                  int* __restrict__ blockSums)
{
    __shared__ int s[256];
    int bx = blockIdx.x;

    if (bx < SCAN_BLOCKS) {
        // ----- scan1 body (block-uniform branch: __syncthreads is legal) -----
        int t = threadIdx.x;
        int base = bx * 1024 + t * 4;
        int c0 = (base + 0 < N_NODES) ? counts[base + 0] : 0;
        int c1 = (base + 1 < N_NODES) ? counts[base + 1] : 0;
        int c2 = (base + 2 < N_NODES) ? counts[base + 2] : 0;
        int c3 = (base + 3 < N_NODES) ? counts[base + 3] : 0;
        int tsum = c0 + c1 + c2 + c3;
        s[t] = tsum;
        __syncthreads();
        for (int off = 1; off < 256; off <<= 1) {
            int v = (t >= off) ? s[t - off] : 0;
            __syncthreads();
            s[t] += v;
            __syncthreads();
        }
        int excl = s[t] - tsum;
        if (base + 0 < N_NODES) offsets[base + 0] = excl;
        if (base + 1 < N_NODES) offsets[base + 1] = excl + c0;
        if (base + 2 < N_NODES) offsets[base + 2] = excl + c0 + c1;
        if (base + 3 < N_NODES) offsets[base + 3] = excl + c0 + c1 + c2;
        if (t == 255) blockSums[bx] = s[255];
        return;
    }

    // ----- lin_att body -----
    int gb = bx - SCAN_BLOCKS;                 // 0 .. 3*GEMM_BLOCKS-1
    const int which = gb / GEMM_BLOCKS;
    const int gx    = gb % GEMM_BLOCKS;

    const float* feat = (which == 0) ? feat0 : (which == 1) ? feat1 : feat2;
    float* sOut = (which == 0) ? p0 : (which == 1) ? q1 : q2;
    unsigned short* Hb = (which == 1) ? H1b : H2b;

    const int t  = threadIdx.x;
    const int wv = t >> 6;
    const int l  = t & 63;
    const int n  = l & 15;
    const int q  = l >> 4;
    const int rowBase = gx * 64 + wv * 16;

    const int gRow = rowBase + n;
    const int lr = (gRow < N_NODES) ? gRow : (N_NODES - 1);   // clamp loads

    // --- issue ALL A loads (8 x dwordx4, HBM/L3) ---
    float4 X[8];
    {
        const float* ap = &feat[(size_t)lr * IN_F + 8 * q];
        #pragma unroll
        for (int ss = 0; ss < 4; ++ss) {
            X[2 * ss]     = *(const float4*)(ap + 32 * ss);
            X[2 * ss + 1] = *(const float4*)(ap + 32 * ss + 4);
        }
    }

    // --- issue ALL B loads (16 x dwordx4, L2 broadcast) ---
    bf16x8 Bf[4][4];
    #pragma unroll
    for (int c = 0; c < 4; ++c)
        #pragma unroll
        for (int ss = 0; ss < 4; ++ss)
            Bf[c][ss] = *(const bf16x8*)&Wpk[((c * 4 + ss) * 64 + l) * 8];

    // --- schedule fence: loads stay issued above (in flight together);
    //     converts/MFMAs stay below. ---
    __builtin_amdgcn_sched_barrier(0);

    f32x4 acc[4];
    #pragma unroll
    for (int c = 0; c < 4; ++c) {
        float bv = b_feat[16 * c + n];
        acc[c][0] = bv; acc[c][1] = bv; acc[c][2] = bv; acc[c][3] = bv;
    }

    #pragma unroll
    for (int ss = 0; ss < 4; ++ss) {
        float4 x0 = X[2 * ss];
        float4 x1 = X[2 * ss + 1];
        bf16x8 a;
        a[0] = f2bf(x0.x); a[1] = f2bf(x0.y); a[2] = f2bf(x0.z); a[3] = f2bf(x0.w);
        a[4] = f2bf(x1.x); a[5] = f2bf(x1.y); a[6] = f2bf(x1.z); a[7] = f2bf(x1.w);
        #pragma unroll
        for (int c = 0; c < 4; ++c)
            acc[c] = __builtin_amdgcn_mfma_f32_16x16x32_bf16(a, Bf[c][ss], acc[c], 0, 0, 0);
    }

    // epilogue: store H (+ fused attention scalar in fp32)
    float part[4] = {0.f, 0.f, 0.f, 0.f};
    #pragma unroll
    for (int c = 0; c < 4; ++c) {
        int col = 16 * c + n;
        float a0 = W_att[col], a1 = W_att[HID + col];
        float ae = (which == 0) ? (a0 + a1 * (1.0f / 3.0f)) : (a1 * (1.0f / 3.0f));
        #pragma unroll
        for (int r = 0; r < 4; ++r) {
            int row = rowBase + 4 * q + r;
            if (row < N_NODES) {
                if (which == 0) H0[(size_t)row * HID + col] = acc[c][r];
                else            Hb[(size_t)row * HID + col] = f2bfu(acc[c][r]);
            }
            part[r] = fmaf(acc[c][r], ae, part[r]);
        }
    }
    #pragma unroll
    for (int r = 0; r < 4; ++r) {
        float p = part[r];
        p += __shfl_xor(p, 1, 64);
        p += __shfl_xor(p, 2, 64);
        p += __shfl_xor(p, 4, 64);
        p += __shfl_xor(p, 8, 64);
        int row = rowBase + 4 * q + r;
        if (n == 0 && row < N_NODES) sOut[row] = p;
    }
}

__global__ __launch_bounds__(128)
void scan2_kernel(int* __restrict__ blockSums)
{
    __shared__ int s[128];
    int t = threadIdx.x;
    int v = (t < SCAN_BLOCKS) ? blockSums[t] : 0;
    s[t] = v;
    __syncthreads();
    for (int off = 1; off < 128; off <<= 1) {
        int u = (t >= off) ? s[t - off] : 0;
        __syncthreads();
        s[t] += u;
        __syncthreads();
    }
    if (t < SCAN_BLOCKS) blockSums[t] = s[t] - v;   // exclusive
}

__global__ __launch_bounds__(256)
void scan3_kernel(int* __restrict__ offsets, int* __restrict__ cursor,
                  const int* __restrict__ blockSums)
{
    int t = threadIdx.x;
    int base = blockIdx.x * 1024 + t * 4;
    int add = blockSums[blockIdx.x];
    #pragma unroll
    for (int k = 0; k < 4; ++k) {
        int i = base + k;
        if (i < N_NODES) {
            int v = offsets[i] + add;
            offsets[i] = v;
            cursor[i] = v;
        }
    }
}

// scatter: edge score + packed record (e1, e2, ex, pad) at dest-sorted pos
// 4 edges/thread via int4 -> 4x gathers/atomics in flight per thread
__global__ __launch_bounds__(256)
void scatter_kernel(const int* __restrict__ e0a, const int* __restrict__ e1a,
                    const int* __restrict__ e2a,
                    const float* __restrict__ p0, const float* __restrict__ q1,
                    const float* __restrict__ q2, const float* __restrict__ b_att,
                    int* __restrict__ cursor, float4* __restrict__ rec)
{
    int i = blockIdx.x * 256 + threadIdx.x;
    if (i < N_EDGES / 4) {
        int4 e0v = ((const int4*)e0a)[i];
        int4 e1v = ((const int4*)e1a)[i];
        int4 e2v = ((const int4*)e2a)[i];
        float ba = b_att[0];

        // four independent gather chains, issued together
        float x0 = p0[e0v.x] + q1[e1v.x] + q2[e2v.x] + ba;
        float x1 = p0[e0v.y] + q1[e1v.y] + q2[e2v.y] + ba;
        float x2 = p0[e0v.z] + q1[e1v.z] + q2[e2v.z] + ba;
        float x3 = p0[e0v.w] + q1[e1v.w] + q2[e2v.w] + ba;
        // tanh in [-1,1] => exp(tanh) safe; softmax shift-invariance makes
        // skipping the segment-max exact.
        float ex0 = __expf(tanhf(x0));
        float ex1 = __expf(tanhf(x1));
        float ex2 = __expf(tanhf(x2));
        float ex3 = __expf(tanhf(x3));

        int pos0 = atomicAdd(&cursor[e0v.x], 1);
        int pos1 = atomicAdd(&cursor[e0v.y], 1);
        int pos2 = atomicAdd(&cursor[e0v.z], 1);
        int pos3 = atomicAdd(&cursor[e0v.w], 1);
        rec[pos0] = make_float4(__int_as_float(e1v.x), __int_as_float(e2v.x), ex0, 0.0f);
        rec[pos1] = make_float4(__int_as_float(e1v.y), __int_as_float(e2v.y), ex1, 0.0f);
        rec[pos2] = make_float4(__int_as_float(e1v.z), __int_as_float(e2v.z), ex2, 0.0f);
        rec[pos3] = make_float4(__int_as_float(e1v.w), __int_as_float(e2v.w), ex3, 0.0f);
    }
}

// ---------------------------------------------------------------------------
// Aggregate (CSR, fused): 16 lanes/node, zero atomics, bf16 gathers.
// j-loop unrolled by 2 -> 2x gather MLP.
// out[n] = bias + H0[n]/3 + (1/(3*sum_ex)) * sum_e ex_e*(H1[e1]+H2[e2])
// ---------------------------------------------------------------------------
__global__ __launch_bounds__(256)
void aggregate_csr_kernel(const int* __restrict__ offsets, const int* __restrict__ counts,
                          const float4* __restrict__ rec,
                          const float* __restrict__ H0,
                          const unsigned short* __restrict__ H1b,
                          const unsigned short* __restrict__ H2b,
                          const float* __restrict__ bias,
                          float* __restrict__ out)
{
    int gid  = blockIdx.x * 256 + threadIdx.x;
    int node = gid >> 4;
    int sub  = gid & 15;
    if (node >= N_NODES) return;

    int start = offsets[node];
    int cnt   = counts[node];

    float denom = 0.0f;
    float ax = 0.0f, ay = 0.0f, az = 0.0f, aw = 0.0f;

    int j = 0;
    for (; j + 2 <= cnt; j += 2) {
        float4 r0 = rec[start + j];
        float4 r1 = rec[start + j + 1];
        int e1_0 = __float_as_int(r0.x), e2_0 = __float_as_int(r0.y);
        int e1_1 = __float_as_int(r1.x), e2_1 = __float_as_int(r1.y);
        u16x4 h1_0 = *(const u16x4*)&H1b[(size_t)e1_0 * HID + 4 * sub];
        u16x4 h2_0 = *(const u16x4*)&H2b[(size_t)e2_0 * HID + 4 * sub];
        u16x4 h1_1 = *(const u16x4*)&H1b[(size_t)e1_1 * HID + 4 * sub];
        u16x4 h2_1 = *(const u16x4*)&H2b[(size_t)e2_1 * HID + 4 * sub];
        float w0 = r0.z, w1 = r1.z;
        denom += w0 + w1;
        ax = fmaf(w0, bf2f(h1_0.x) + bf2f(h2_0.x), ax);
        ay = fmaf(w0, bf2f(h1_0.y) + bf2f(h2_0.y), ay);
        az = fmaf(w0, bf2f(h1_0.z) + bf2f(h2_0.z), az);
        aw = fmaf(w0, bf2f(h1_0.w) + bf2f(h2_0.w), aw);
        ax = fmaf(w1, bf2f(h1_1.x) + bf2f(h2_1.x), ax);
        ay = fmaf(w1, bf2f(h1_1.y) + bf2f(h2_1.y), ay);
        az = fmaf(w1, bf2f(h1_1.z) + bf2f(h2_1.z), az);
        aw = fmaf(w1, bf2f(h1_1.w) + bf2f(h2_1.w), aw);
    }
    if (j < cnt) {
        float4 r = rec[start + j];
        int e1 = __float_as_int(r.x);
        int e2 = __float_as_int(r.y);
        float w = r.z;
        u16x4 h1 = *(const u16x4*)&H1b[(size_t)e1 * HID + 4 * sub];
        u16x4 h2 = *(const u16x4*)&H2b[(size_t)e2 * HID + 4 * sub];
        denom += w;
        ax = fmaf(w, bf2f(h1.x) + bf2f(h2.x), ax);
        ay = fmaf(w, bf2f(h1.y) + bf2f(h2.y), ay);
        az = fmaf(w, bf2f(h1.z) + bf2f(h2.z), az);
        aw = fmaf(w, bf2f(h1.w) + bf2f(h2.w), aw);
    }

    float4 h0 = *(const float4*)&H0[(size_t)node * HID + 4 * sub];
    float4 bv = *(const float4*)&bias[4 * sub];
    float third = (cnt > 0) ? (1.0f / 3.0f) : 0.0f;
    float inv   = (cnt > 0) ? 1.0f / (3.0f * denom) : 0.0f;

    float4 o;
    o.x = bv.x + third * h0.x + inv * ax;
    o.y = bv.y + third * h0.y + inv * ay;
    o.z = bv.z + third * h0.z + inv * az;
    o.w = bv.w + third * h0.w + inv * aw;
    *(float4*)&out[(size_t)node * HID + 4 * sub] = o;
}

// ---------------------------------------------------------------------------
extern "C" void kernel_launch(void* const* d_in, const int* in_sizes, int n_in,
                              void* d_out, int out_size, void* d_ws, size_t ws_size,
                              hipStream_t stream)
{
    const float* feat0  = (const float*)d_in[0];
    const float* feat1  = (const float*)d_in[1];
    const float* feat2  = (const float*)d_in[2];
    const int*   edge0  = (const int*)d_in[3];
    const int*   edge1  = (const int*)d_in[4];
    const int*   edge2  = (const int*)d_in[5];
    const float* W_feat = (const float*)d_in[6];
    const float* b_feat = (const float*)d_in[7];
    const float* W_att  = (const float*)d_in[8];
    const float* b_att  = (const float*)d_in[9];
    const float* bias   = (const float*)d_in[10];
    float* out = (float*)d_out;

    // workspace layout (16B-aligned chunks first)
    float4* rec  = (float4*)d_ws;                          // 1M float4 = 16 MB
    short*  Wpk  = (short*)(rec + N_EDGES);                // 8192 shorts (16 KB)
    float*  H0   = (float*)(Wpk + 8192);                   // 6.4M floats
    unsigned short* H1b = (unsigned short*)(H0 + (size_t)N_NODES * HID); // 6.4M
    unsigned short* H2b = H1b + (size_t)N_NODES * HID;                   // 6.4M
    float*  p0   = (float*)(H2b + (size_t)N_NODES * HID);
    float*  q1   = p0 + N_NODES;
    float*  q2   = q1 + N_NODES;
    int* counts    = (int*)(q2 + N_NODES);
    int* offsets   = counts + N_NODES;
    int* cursor    = offsets + N_NODES;
    int* blockSums = cursor + N_NODES;                     // 128
    // total ~72 MB

    (void)hipMemsetAsync(counts, 0, N_NODES * sizeof(int), stream);

    dim3 blk(256);

    // K1: pack_w (4 blocks) ∥ hist (977 blocks)
    k1_pack_hist<<<4 + (N_EDGES / 4 + 255) / 256, blk, 0, stream>>>(
        W_feat, Wpk, edge0, counts);

    // K2: scan1 (98 blocks) ∥ lin_att (4689 blocks)
    k2_lin_scan1<<<SCAN_BLOCKS + 3 * GEMM_BLOCKS, blk, 0, stream>>>(
        feat0, feat1, feat2, Wpk, b_feat, W_att,
        H0, H1b, H2b, p0, q1, q2,
        counts, offsets, blockSums);

    scan2_kernel<<<1, 128, 0, stream>>>(blockSums);
    scan3_kernel<<<SCAN_BLOCKS, blk, 0, stream>>>(offsets, cursor, blockSums);

    scatter_kernel<<<(N_EDGES / 4 + 255) / 256, blk, 0, stream>>>(
        edge0, edge1, edge2, p0, q1, q2, b_att, cursor, rec);

    aggregate_csr_kernel<<<((size_t)N_NODES * 16 + 255) / 256, blk, 0, stream>>>(
        offsets, counts, rec, H0, H1b, H2b, bias, out);
}

// Round 5
// 317.049 us; speedup vs baseline: 1.1351x; 1.1089x over previous
//
#include <hip/hip_runtime.h>
#include <math.h>

#define IN_F 128
#define HID 64
#define N_NODES 100000
#define N_EDGES 1000000
#define GEMM_BLOCKS 1563 // ceil(N_NODES / 64)

typedef __attribute__((ext_vector_type(8))) short bf16x8;
typedef __attribute__((ext_vector_type(4))) float f32x4;
typedef __attribute__((ext_vector_type(4))) unsigned short u16x4;

// round-to-nearest-even fp32 -> bf16 (inputs finite)
static __device__ __forceinline__ short f2bf(float f) {
    union { float f; unsigned u; } v; v.f = f;
    unsigned r = v.u + 0x7fffu + ((v.u >> 16) & 1u);
    return (short)(r >> 16);
}
static __device__ __forceinline__ unsigned short f2bfu(float f) {
    union { float f; unsigned u; } v; v.f = f;
    unsigned r = v.u + 0x7fffu + ((v.u >> 16) & 1u);
    return (unsigned short)(r >> 16);
}
static __device__ __forceinline__ float bf2f(unsigned short u) {
    union { unsigned u; float f; } v; v.u = ((unsigned)u) << 16; return v.f;
}

// ---------------------------------------------------------------------------
// K1: pack W into bf16 B-fragment layout (blocks 0..3) ∥ head[]=-1 init
// (blocks 4..101). Replaces pack_w + hipMemset(counts); the whole CSR
// build (hist + 3 scans) is deleted in this version.
//   Wpk entry (c*4+s)*64 + l holds 8 bf16 = W[k][16c+n], k=32s+8q+j, l=16q+n
// ---------------------------------------------------------------------------
__global__ __launch_bounds__(256)
void k1_pack_init(const float* __restrict__ W, short* __restrict__ Wpk,
                  int* __restrict__ head)
{
    int bx = blockIdx.x;
    if (bx < 4) {
        int i = bx * 256 + threadIdx.x;   // 1024 entries
        if (i < 1024) {
            int l = i & 63, cs = i >> 6;
            int c = cs >> 2, s = cs & 3;
            int n = l & 15, q = l >> 4;
            short v[8];
            #pragma unroll
            for (int j = 0; j < 8; ++j)
                v[j] = f2bf(W[(32 * s + 8 * q + j) * HID + 16 * c + n]);
            *(bf16x8*)&Wpk[(size_t)i * 8] = *(const bf16x8*)v;
        }
    } else {
        int i4 = (bx - 4) * 256 + threadIdx.x;     // int4 index
        if (i4 < N_NODES / 4)
            ((int4*)head)[i4] = make_int4(-1, -1, -1, -1);
    }
}

// ---------------------------------------------------------------------------
// Fused 3x GEMM via bf16 MFMA, zero LDS / zero syncthreads (74 us measured).
//   All 24 loads (8 A + 16 B) issued up front + sched_barrier(0) fence so
//   the compiler cannot re-sink them. One wait, 16 back-to-back MFMAs.
//   A-frag: lane m=l&15, k=8*quad+j  (global fp32 -> inline bf16)
//   B-frag: from pre-packed Wpk (coalesced 16B loads, L2-hot)
//   C/D:    col=l&15, row=4*quad+reg  [m89/m91 verified]
// which==0 -> H0 fp32 + p0 ; which==1/2 -> H bf16 + q1/q2
// ---------------------------------------------------------------------------
__global__ __launch_bounds__(256)
void lin_att_mfma(const float* __restrict__ feat0, const float* __restrict__ feat1,
                  const float* __restrict__ feat2,
                  const short* __restrict__ Wpk, const float* __restrict__ b_feat,
                  const float* __restrict__ W_att,
                  float* __restrict__ H0,
                  unsigned short* __restrict__ H1b, unsigned short* __restrict__ H2b,
                  float* __restrict__ p0, float* __restrict__ q1, float* __restrict__ q2)
{
    const int which = blockIdx.y;
    const float* feat = (which == 0) ? feat0 : (which == 1) ? feat1 : feat2;
    float* sOut = (which == 0) ? p0 : (which == 1) ? q1 : q2;
    unsigned short* Hb = (which == 1) ? H1b : H2b;

    const int t  = threadIdx.x;
    const int wv = t >> 6;
    const int l  = t & 63;
    const int n  = l & 15;
    const int q  = l >> 4;
    const int rowBase = blockIdx.x * 64 + wv * 16;

    const int gRow = rowBase + n;
    const int lr = (gRow < N_NODES) ? gRow : (N_NODES - 1);   // clamp loads

    // --- issue ALL A loads (8 x dwordx4, HBM/L3) ---
    float4 X[8];
    {
        const float* ap = &feat[(size_t)lr * IN_F + 8 * q];
        #pragma unroll
        for (int ss = 0; ss < 4; ++ss) {
            X[2 * ss]     = *(const float4*)(ap + 32 * ss);
            X[2 * ss + 1] = *(const float4*)(ap + 32 * ss + 4);
        }
    }

    // --- issue ALL B loads (16 x dwordx4, L2 broadcast) ---
    bf16x8 Bf[4][4];
    #pragma unroll
    for (int c = 0; c < 4; ++c)
        #pragma unroll
        for (int ss = 0; ss < 4; ++ss)
            Bf[c][ss] = *(const bf16x8*)&Wpk[((c * 4 + ss) * 64 + l) * 8];

    // --- schedule fence: loads stay above (in flight together) ---
    __builtin_amdgcn_sched_barrier(0);

    f32x4 acc[4];
    #pragma unroll
    for (int c = 0; c < 4; ++c) {
        float bv = b_feat[16 * c + n];
        acc[c][0] = bv; acc[c][1] = bv; acc[c][2] = bv; acc[c][3] = bv;
    }

    #pragma unroll
    for (int ss = 0; ss < 4; ++ss) {
        float4 x0 = X[2 * ss];
        float4 x1 = X[2 * ss + 1];
        bf16x8 a;
        a[0] = f2bf(x0.x); a[1] = f2bf(x0.y); a[2] = f2bf(x0.z); a[3] = f2bf(x0.w);
        a[4] = f2bf(x1.x); a[5] = f2bf(x1.y); a[6] = f2bf(x1.z); a[7] = f2bf(x1.w);
        #pragma unroll
        for (int c = 0; c < 4; ++c)
            acc[c] = __builtin_amdgcn_mfma_f32_16x16x32_bf16(a, Bf[c][ss], acc[c], 0, 0, 0);
    }

    // epilogue: store H (+ fused attention scalar in fp32)
    float part[4] = {0.f, 0.f, 0.f, 0.f};
    #pragma unroll
    for (int c = 0; c < 4; ++c) {
        int col = 16 * c + n;
        float a0 = W_att[col], a1 = W_att[HID + col];
        float ae = (which == 0) ? (a0 + a1 * (1.0f / 3.0f)) : (a1 * (1.0f / 3.0f));
        #pragma unroll
        for (int r = 0; r < 4; ++r) {
            int row = rowBase + 4 * q + r;
            if (row < N_NODES) {
                if (which == 0) H0[(size_t)row * HID + col] = acc[c][r];
                else            Hb[(size_t)row * HID + col] = f2bfu(acc[c][r]);
            }
            part[r] = fmaf(acc[c][r], ae, part[r]);
        }
    }
    #pragma unroll
    for (int r = 0; r < 4; ++r) {
        float p = part[r];
        p += __shfl_xor(p, 1, 64);
        p += __shfl_xor(p, 2, 64);
        p += __shfl_xor(p, 4, 64);
        p += __shfl_xor(p, 8, 64);
        int row = rowBase + 4 * q + r;
        if (n == 0 && row < N_NODES) sOut[row] = p;
    }
}

// ---------------------------------------------------------------------------
// link: ONE atomic pass builds per-node linked lists. Replaces hist + scans +
// scatter (two 1M-atomic passes + 64 MB amplified writeback) with:
//   old = atomicExch(&head[e0], i)          -- the only random-access write
//   rec[i] = (e1, e2, ex, next=old)         -- COALESCED sequential float4
// next pointer rides in rec.w: the walk needs one 16B load per step and
// there is no separate next[] array. 4 edges/thread for MLP.
// ---------------------------------------------------------------------------
__global__ __launch_bounds__(256)
void link_kernel(const int* __restrict__ e0a, const int* __restrict__ e1a,
                 const int* __restrict__ e2a,
                 const float* __restrict__ p0, const float* __restrict__ q1,
                 const float* __restrict__ q2, const float* __restrict__ b_att,
                 int* __restrict__ head, float4* __restrict__ rec)
{
    int i = blockIdx.x * 256 + threadIdx.x;
    if (i < N_EDGES / 4) {
        int4 e0v = ((const int4*)e0a)[i];
        int4 e1v = ((const int4*)e1a)[i];
        int4 e2v = ((const int4*)e2a)[i];
        float ba = b_att[0];

        // four independent gather chains, issued together
        float x0 = p0[e0v.x] + q1[e1v.x] + q2[e2v.x] + ba;
        float x1 = p0[e0v.y] + q1[e1v.y] + q2[e2v.y] + ba;
        float x2 = p0[e0v.z] + q1[e1v.z] + q2[e2v.z] + ba;
        float x3 = p0[e0v.w] + q1[e1v.w] + q2[e2v.w] + ba;
        // tanh in [-1,1] => exp(tanh) safe; softmax shift-invariance makes
        // skipping the segment-max exact.
        float ex0 = __expf(tanhf(x0));
        float ex1 = __expf(tanhf(x1));
        float ex2 = __expf(tanhf(x2));
        float ex3 = __expf(tanhf(x3));

        int base = i * 4;
        int old0 = atomicExch(&head[e0v.x], base + 0);
        int old1 = atomicExch(&head[e0v.y], base + 1);
        int old2 = atomicExch(&head[e0v.z], base + 2);
        int old3 = atomicExch(&head[e0v.w], base + 3);

        // sequential, coalesced 16B stores (the scattered-store path is gone)
        rec[base + 0] = make_float4(__int_as_float(e1v.x), __int_as_float(e2v.x), ex0, __int_as_float(old0));
        rec[base + 1] = make_float4(__int_as_float(e1v.y), __int_as_float(e2v.y), ex1, __int_as_float(old1));
        rec[base + 2] = make_float4(__int_as_float(e1v.z), __int_as_float(e2v.z), ex2, __int_as_float(old2));
        rec[base + 3] = make_float4(__int_as_float(e1v.w), __int_as_float(e2v.w), ex3, __int_as_float(old3));
    }
}

// ---------------------------------------------------------------------------
// Aggregate (linked-list walk): 16 lanes/node, zero atomics, bf16 gathers.
// Walk: j = head[n]; step j = rec[j].w. rec is LLC-hot (just written);
// rec[j] load is broadcast across the 16 lanes; H gathers are coalesced
// 128B rows. out[n] = bias + H0[n]/3 + (1/(3*sum_ex)) * sum ex*(H1+H2)
// ---------------------------------------------------------------------------
__global__ __launch_bounds__(256)
void aggregate_ll_kernel(const int* __restrict__ head,
                         const float4* __restrict__ rec,
                         const float* __restrict__ H0,
                         const unsigned short* __restrict__ H1b,
                         const unsigned short* __restrict__ H2b,
                         const float* __restrict__ bias,
                         float* __restrict__ out)
{
    int gid  = blockIdx.x * 256 + threadIdx.x;
    int node = gid >> 4;
    int sub  = gid & 15;
    if (node >= N_NODES) return;

    int j = head[node];
    const bool hasEdges = (j >= 0);

    float denom = 0.0f;
    float ax = 0.0f, ay = 0.0f, az = 0.0f, aw = 0.0f;
    while (j >= 0) {
        float4 r = rec[j];                 // one 16B broadcast load per step
        int e1 = __float_as_int(r.x);
        int e2 = __float_as_int(r.y);
        float w = r.z;
        int nj = __float_as_int(r.w);      // next pointer rides in .w
        u16x4 h1 = *(const u16x4*)&H1b[(size_t)e1 * HID + 4 * sub];
        u16x4 h2 = *(const u16x4*)&H2b[(size_t)e2 * HID + 4 * sub];
        denom += w;
        ax = fmaf(w, bf2f(h1.x) + bf2f(h2.x), ax);
        ay = fmaf(w, bf2f(h1.y) + bf2f(h2.y), ay);
        az = fmaf(w, bf2f(h1.z) + bf2f(h2.z), az);
        aw = fmaf(w, bf2f(h1.w) + bf2f(h2.w), aw);
        j = nj;
    }

    float4 h0 = *(const float4*)&H0[(size_t)node * HID + 4 * sub];
    float4 bv = *(const float4*)&bias[4 * sub];
    float third = hasEdges ? (1.0f / 3.0f) : 0.0f;
    float inv   = hasEdges ? 1.0f / (3.0f * denom) : 0.0f;

    float4 o;
    o.x = bv.x + third * h0.x + inv * ax;
    o.y = bv.y + third * h0.y + inv * ay;
    o.z = bv.z + third * h0.z + inv * az;
    o.w = bv.w + third * h0.w + inv * aw;
    *(float4*)&out[(size_t)node * HID + 4 * sub] = o;
}

// ---------------------------------------------------------------------------
extern "C" void kernel_launch(void* const* d_in, const int* in_sizes, int n_in,
                              void* d_out, int out_size, void* d_ws, size_t ws_size,
                              hipStream_t stream)
{
    const float* feat0  = (const float*)d_in[0];
    const float* feat1  = (const float*)d_in[1];
    const float* feat2  = (const float*)d_in[2];
    const int*   edge0  = (const int*)d_in[3];
    const int*   edge1  = (const int*)d_in[4];
    const int*   edge2  = (const int*)d_in[5];
    const float* W_feat = (const float*)d_in[6];
    const float* b_feat = (const float*)d_in[7];
    const float* W_att  = (const float*)d_in[8];
    const float* b_att  = (const float*)d_in[9];
    const float* bias   = (const float*)d_in[10];
    float* out = (float*)d_out;

    // workspace layout (16B-aligned chunks first)
    float4* rec  = (float4*)d_ws;                          // 1M float4 = 16 MB
    short*  Wpk  = (short*)(rec + N_EDGES);                // 8192 shorts (16 KB)
    float*  H0   = (float*)(Wpk + 8192);                   // 6.4M floats
    unsigned short* H1b = (unsigned short*)(H0 + (size_t)N_NODES * HID); // 6.4M
    unsigned short* H2b = H1b + (size_t)N_NODES * HID;                   // 6.4M
    float*  p0   = (float*)(H2b + (size_t)N_NODES * HID);
    float*  q1   = p0 + N_NODES;
    float*  q2   = q1 + N_NODES;
    int*    head = (int*)(q2 + N_NODES);                   // 100K ints
    // total ~71 MB

    dim3 blk(256);

    // K1: pack_w (4 blocks) ∥ head=-1 init (98 blocks)
    k1_pack_init<<<4 + (N_NODES / 4 + 255) / 256, blk, 0, stream>>>(
        W_feat, Wpk, head);

    // K2: fused 3x GEMM + attention partials
    dim3 gemmGrid(GEMM_BLOCKS, 3);
    lin_att_mfma<<<gemmGrid, blk, 0, stream>>>(feat0, feat1, feat2,
                                               Wpk, b_feat, W_att,
                                               H0, H1b, H2b, p0, q1, q2);

    // K3: single atomic pass builds per-node lists, all stores coalesced
    link_kernel<<<(N_EDGES / 4 + 255) / 256, blk, 0, stream>>>(
        edge0, edge1, edge2, p0, q1, q2, b_att, head, rec);

    // K4: list-walk aggregation
    aggregate_ll_kernel<<<((size_t)N_NODES * 16 + 255) / 256, blk, 0, stream>>>(
        head, rec, H0, H1b, H2b, bias, out);
}

// Round 6
// 313.224 us; speedup vs baseline: 1.1489x; 1.0122x over previous
//
#include <hip/hip_runtime.h>
#include <math.h>

#define IN_F 128
#define HID 64
#define N_NODES 100000
#define N_EDGES 1000000
#define GEMM_BLOCKS 1563 // ceil(N_NODES / 64)

typedef __attribute__((ext_vector_type(8))) short bf16x8;
typedef __attribute__((ext_vector_type(4))) float f32x4;
typedef __attribute__((ext_vector_type(4))) unsigned short u16x4;

// round-to-nearest-even fp32 -> bf16 (inputs finite)
static __device__ __forceinline__ short f2bf(float f) {
    union { float f; unsigned u; } v; v.f = f;
    unsigned r = v.u + 0x7fffu + ((v.u >> 16) & 1u);
    return (short)(r >> 16);
}
static __device__ __forceinline__ unsigned short f2bfu(float f) {
    union { float f; unsigned u; } v; v.f = f;
    unsigned r = v.u + 0x7fffu + ((v.u >> 16) & 1u);
    return (unsigned short)(r >> 16);
}
static __device__ __forceinline__ float bf2f(unsigned short u) {
    union { unsigned u; float f; } v; v.u = ((unsigned)u) << 16; return v.f;
}

// ---------------------------------------------------------------------------
// K1: pack W into bf16 B-fragment layout (blocks 0..3) ∥ head[]=-1 init
// (blocks 4..101).
//   Wpk entry (c*4+s)*64 + l holds 8 bf16 = W[k][16c+n], k=32s+8q+j, l=16q+n
// ---------------------------------------------------------------------------
__global__ __launch_bounds__(256)
void k1_pack_init(const float* __restrict__ W, short* __restrict__ Wpk,
                  int* __restrict__ head)
{
    int bx = blockIdx.x;
    if (bx < 4) {
        int i = bx * 256 + threadIdx.x;   // 1024 entries
        if (i < 1024) {
            int l = i & 63, cs = i >> 6;
            int c = cs >> 2, s = cs & 3;
            int n = l & 15, q = l >> 4;
            short v[8];
            #pragma unroll
            for (int j = 0; j < 8; ++j)
                v[j] = f2bf(W[(32 * s + 8 * q + j) * HID + 16 * c + n]);
            *(bf16x8*)&Wpk[(size_t)i * 8] = *(const bf16x8*)v;
        }
    } else {
        int i4 = (bx - 4) * 256 + threadIdx.x;     // int4 index
        if (i4 < N_NODES / 4)
            ((int4*)head)[i4] = make_int4(-1, -1, -1, -1);
    }
}

// ---------------------------------------------------------------------------
// Fused 3x GEMM via bf16 MFMA.
// v7: B-fragments via LDS. v4/v5's VGPR=68 proved sched_barrier never kept
//     the 16 B-loads in flight (would need >=128 VGPR live) — IR-level
//     sinking moved them across the fence. LDS staging is structural: the
//     VMEM queue now carries ONLY the 8 independent A-loads; ds_read_b128
//     fragments pipeline against MFMA (compiler's lgkmcnt scheduling is
//     near-optimal per m97 asm). B L2-traffic also drops 4x (per-block
//     16 KB instead of per-wave).
//   A-frag: lane m=l&15, k=8*quad+j  (global fp32 -> inline bf16)
//   C/D:    col=l&15, row=4*quad+reg  [m89/m91 verified]
// which==0 -> H0 fp32 + p0 ; which==1/2 -> H bf16 + q1/q2
// ---------------------------------------------------------------------------
__global__ __launch_bounds__(256)
void lin_att_mfma(const float* __restrict__ feat0, const float* __restrict__ feat1,
                  const float* __restrict__ feat2,
                  const short* __restrict__ Wpk, const float* __restrict__ b_feat,
                  const float* __restrict__ W_att,
                  float* __restrict__ H0,
                  unsigned short* __restrict__ H1b, unsigned short* __restrict__ H2b,
                  float* __restrict__ p0, float* __restrict__ q1, float* __restrict__ q2)
{
    __shared__ short Wlds[8192];   // 16 KB: whole packed W, shared by 4 waves

    const int which = blockIdx.y;
    const float* feat = (which == 0) ? feat0 : (which == 1) ? feat1 : feat2;
    float* sOut = (which == 0) ? p0 : (which == 1) ? q1 : q2;
    unsigned short* Hb = (which == 1) ? H1b : H2b;

    const int t  = threadIdx.x;
    const int wv = t >> 6;
    const int l  = t & 63;
    const int n  = l & 15;
    const int q  = l >> 4;
    const int rowBase = blockIdx.x * 64 + wv * 16;

    const int gRow = rowBase + n;
    const int lr = (gRow < N_NODES) ? gRow : (N_NODES - 1);   // clamp loads

    // --- issue the 8 independent A loads first (only VMEM in the hot path) ---
    f32x4 X[8];
    {
        const float* ap = &feat[(size_t)lr * IN_F + 8 * q];
        #pragma unroll
        for (int ss = 0; ss < 4; ++ss) {
            X[2 * ss]     = *(const f32x4*)(ap + 32 * ss);
            X[2 * ss + 1] = *(const f32x4*)(ap + 32 * ss + 4);
        }
    }

    // --- stage W (16 KB) into LDS once per block, 4 x 16B per thread;
    //     these loads overlap the A-loads already in flight ---
    #pragma unroll
    for (int it = 0; it < 4; ++it) {
        int idx = it * 256 + t;            // entry 0..1023
        *(bf16x8*)&Wlds[idx * 8] = *(const bf16x8*)&Wpk[(size_t)idx * 8];
    }
    __syncthreads();

    f32x4 acc[4];
    #pragma unroll
    for (int c = 0; c < 4; ++c) {
        float bv = b_feat[16 * c + n];
        acc[c][0] = bv; acc[c][1] = bv; acc[c][2] = bv; acc[c][3] = bv;
    }

    #pragma unroll
    for (int ss = 0; ss < 4; ++ss) {
        f32x4 x0 = X[2 * ss];
        f32x4 x1 = X[2 * ss + 1];
        bf16x8 a;
        a[0] = f2bf(x0[0]); a[1] = f2bf(x0[1]); a[2] = f2bf(x0[2]); a[3] = f2bf(x0[3]);
        a[4] = f2bf(x1[0]); a[5] = f2bf(x1[1]); a[6] = f2bf(x1[2]); a[7] = f2bf(x1[3]);
        #pragma unroll
        for (int c = 0; c < 4; ++c) {
            bf16x8 bfr = *(const bf16x8*)&Wlds[((c * 4 + ss) * 64 + l) * 8];
            acc[c] = __builtin_amdgcn_mfma_f32_16x16x32_bf16(a, bfr, acc[c], 0, 0, 0);
        }
    }

    // epilogue: store H (+ fused attention scalar in fp32)
    float part[4] = {0.f, 0.f, 0.f, 0.f};
    #pragma unroll
    for (int c = 0; c < 4; ++c) {
        int col = 16 * c + n;
        float a0 = W_att[col], a1 = W_att[HID + col];
        float ae = (which == 0) ? (a0 + a1 * (1.0f / 3.0f)) : (a1 * (1.0f / 3.0f));
        #pragma unroll
        for (int r = 0; r < 4; ++r) {
            int row = rowBase + 4 * q + r;
            if (row < N_NODES) {
                if (which == 0) H0[(size_t)row * HID + col] = acc[c][r];
                else            Hb[(size_t)row * HID + col] = f2bfu(acc[c][r]);
            }
            part[r] = fmaf(acc[c][r], ae, part[r]);
        }
    }
    #pragma unroll
    for (int r = 0; r < 4; ++r) {
        float p = part[r];
        p += __shfl_xor(p, 1, 64);
        p += __shfl_xor(p, 2, 64);
        p += __shfl_xor(p, 4, 64);
        p += __shfl_xor(p, 8, 64);
        int row = rowBase + 4 * q + r;
        if (n == 0 && row < N_NODES) sOut[row] = p;
    }
}

// ---------------------------------------------------------------------------
// link: ONE atomic pass builds per-node linked lists.
//   old = atomicExch(&head[e0], i)          -- the only random-access write
//   rec[i] = (e1, e2, ex, next=old)         -- COALESCED sequential float4
// ---------------------------------------------------------------------------
__global__ __launch_bounds__(256)
void link_kernel(const int* __restrict__ e0a, const int* __restrict__ e1a,
                 const int* __restrict__ e2a,
                 const float* __restrict__ p0, const float* __restrict__ q1,
                 const float* __restrict__ q2, const float* __restrict__ b_att,
                 int* __restrict__ head, float4* __restrict__ rec)
{
    int i = blockIdx.x * 256 + threadIdx.x;
    if (i < N_EDGES / 4) {
        int4 e0v = ((const int4*)e0a)[i];
        int4 e1v = ((const int4*)e1a)[i];
        int4 e2v = ((const int4*)e2a)[i];
        float ba = b_att[0];

        // four independent gather chains, issued together
        float x0 = p0[e0v.x] + q1[e1v.x] + q2[e2v.x] + ba;
        float x1 = p0[e0v.y] + q1[e1v.y] + q2[e2v.y] + ba;
        float x2 = p0[e0v.z] + q1[e1v.z] + q2[e2v.z] + ba;
        float x3 = p0[e0v.w] + q1[e1v.w] + q2[e2v.w] + ba;
        // tanh in [-1,1] => exp(tanh) safe; softmax shift-invariance makes
        // skipping the segment-max exact.
        float ex0 = __expf(tanhf(x0));
        float ex1 = __expf(tanhf(x1));
        float ex2 = __expf(tanhf(x2));
        float ex3 = __expf(tanhf(x3));

        int base = i * 4;
        int old0 = atomicExch(&head[e0v.x], base + 0);
        int old1 = atomicExch(&head[e0v.y], base + 1);
        int old2 = atomicExch(&head[e0v.z], base + 2);
        int old3 = atomicExch(&head[e0v.w], base + 3);

        // sequential, coalesced 16B stores
        rec[base + 0] = make_float4(__int_as_float(e1v.x), __int_as_float(e2v.x), ex0, __int_as_float(old0));
        rec[base + 1] = make_float4(__int_as_float(e1v.y), __int_as_float(e2v.y), ex1, __int_as_float(old1));
        rec[base + 2] = make_float4(__int_as_float(e1v.z), __int_as_float(e2v.z), ex2, __int_as_float(old2));
        rec[base + 3] = make_float4(__int_as_float(e1v.w), __int_as_float(e2v.w), ex3, __int_as_float(old3));
    }
}

// ---------------------------------------------------------------------------
// Aggregate (linked-list walk): 16 lanes/node, zero atomics, bf16 gathers.
// Walk: j = head[n]; step j = rec[j].w (next pointer rides in .w).
// out[n] = bias + H0[n]/3 + (1/(3*sum_ex)) * sum ex*(H1+H2)
// ---------------------------------------------------------------------------
__global__ __launch_bounds__(256)
void aggregate_ll_kernel(const int* __restrict__ head,
                         const float4* __restrict__ rec,
                         const float* __restrict__ H0,
                         const unsigned short* __restrict__ H1b,
                         const unsigned short* __restrict__ H2b,
                         const float* __restrict__ bias,
                         float* __restrict__ out)
{
    int gid  = blockIdx.x * 256 + threadIdx.x;
    int node = gid >> 4;
    int sub  = gid & 15;
    if (node >= N_NODES) return;

    int j = head[node];
    const bool hasEdges = (j >= 0);

    float denom = 0.0f;
    float ax = 0.0f, ay = 0.0f, az = 0.0f, aw = 0.0f;
    while (j >= 0) {
        float4 r = rec[j];                 // one 16B broadcast load per step
        int e1 = __float_as_int(r.x);
        int e2 = __float_as_int(r.y);
        float w = r.z;
        int nj = __float_as_int(r.w);      // next pointer rides in .w
        u16x4 h1 = *(const u16x4*)&H1b[(size_t)e1 * HID + 4 * sub];
        u16x4 h2 = *(const u16x4*)&H2b[(size_t)e2 * HID + 4 * sub];
        denom += w;
        ax = fmaf(w, bf2f(h1.x) + bf2f(h2.x), ax);
        ay = fmaf(w, bf2f(h1.y) + bf2f(h2.y), ay);
        az = fmaf(w, bf2f(h1.z) + bf2f(h2.z), az);
        aw = fmaf(w, bf2f(h1.w) + bf2f(h2.w), aw);
        j = nj;
    }

    float4 h0 = *(const float4*)&H0[(size_t)node * HID + 4 * sub];
    float4 bv = *(const float4*)&bias[4 * sub];
    float third = hasEdges ? (1.0f / 3.0f) : 0.0f;
    float inv   = hasEdges ? 1.0f / (3.0f * denom) : 0.0f;

    float4 o;
    o.x = bv.x + third * h0.x + inv * ax;
    o.y = bv.y + third * h0.y + inv * ay;
    o.z = bv.z + third * h0.z + inv * az;
    o.w = bv.w + third * h0.w + inv * aw;
    *(float4*)&out[(size_t)node * HID + 4 * sub] = o;
}

// ---------------------------------------------------------------------------
extern "C" void kernel_launch(void* const* d_in, const int* in_sizes, int n_in,
                              void* d_out, int out_size, void* d_ws, size_t ws_size,
                              hipStream_t stream)
{
    const float* feat0  = (const float*)d_in[0];
    const float* feat1  = (const float*)d_in[1];
    const float* feat2  = (const float*)d_in[2];
    const int*   edge0  = (const int*)d_in[3];
    const int*   edge1  = (const int*)d_in[4];
    const int*   edge2  = (const int*)d_in[5];
    const float* W_feat = (const float*)d_in[6];
    const float* b_feat = (const float*)d_in[7];
    const float* W_att  = (const float*)d_in[8];
    const float* b_att  = (const float*)d_in[9];
    const float* bias   = (const float*)d_in[10];
    float* out = (float*)d_out;

    // workspace layout (16B-aligned chunks first)
    float4* rec  = (float4*)d_ws;                          // 1M float4 = 16 MB
    short*  Wpk  = (short*)(rec + N_EDGES);                // 8192 shorts (16 KB)
    float*  H0   = (float*)(Wpk + 8192);                   // 6.4M floats
    unsigned short* H1b = (unsigned short*)(H0 + (size_t)N_NODES * HID); // 6.4M
    unsigned short* H2b = H1b + (size_t)N_NODES * HID;                   // 6.4M
    float*  p0   = (float*)(H2b + (size_t)N_NODES * HID);
    float*  q1   = p0 + N_NODES;
    float*  q2   = q1 + N_NODES;
    int*    head = (int*)(q2 + N_NODES);                   // 100K ints
    // total ~71 MB

    dim3 blk(256);

    // K1: pack_w (4 blocks) ∥ head=-1 init (98 blocks)
    k1_pack_init<<<4 + (N_NODES / 4 + 255) / 256, blk, 0, stream>>>(
        W_feat, Wpk, head);

    // K2: fused 3x GEMM + attention partials
    dim3 gemmGrid(GEMM_BLOCKS, 3);
    lin_att_mfma<<<gemmGrid, blk, 0, stream>>>(feat0, feat1, feat2,
                                               Wpk, b_feat, W_att,
                                               H0, H1b, H2b, p0, q1, q2);

    // K3: single atomic pass builds per-node lists, all stores coalesced
    link_kernel<<<(N_EDGES / 4 + 255) / 256, blk, 0, stream>>>(
        edge0, edge1, edge2, p0, q1, q2, b_att, head, rec);

    // K4: list-walk aggregation
    aggregate_ll_kernel<<<((size_t)N_NODES * 16 + 255) / 256, blk, 0, stream>>>(
        head, rec, H0, H1b, H2b, bias, out);
}

// Round 7
// 310.415 us; speedup vs baseline: 1.1593x; 1.0091x over previous
//
#include <hip/hip_runtime.h>
#include <math.h>

#define IN_F 128
#define HID 64
#define N_NODES 100000
#define N_EDGES 1000000
#define GEMM_BLOCKS 1563 // ceil(N_NODES / 64)
#define LINK_BLOCKS 977  // ceil((N_EDGES/4) / 256)

typedef __attribute__((ext_vector_type(8))) short bf16x8;
typedef __attribute__((ext_vector_type(4))) float f32x4;
typedef __attribute__((ext_vector_type(4))) unsigned short u16x4;

// round-to-nearest-even fp32 -> bf16 (inputs finite)
static __device__ __forceinline__ short f2bf(float f) {
    union { float f; unsigned u; } v; v.f = f;
    unsigned r = v.u + 0x7fffu + ((v.u >> 16) & 1u);
    return (short)(r >> 16);
}
static __device__ __forceinline__ unsigned short f2bfu(float f) {
    union { float f; unsigned u; } v; v.f = f;
    unsigned r = v.u + 0x7fffu + ((v.u >> 16) & 1u);
    return (unsigned short)(r >> 16);
}
static __device__ __forceinline__ float bf2f(unsigned short u) {
    union { unsigned u; float f; } v; v.u = ((unsigned)u) << 16; return v.f;
}

// ---------------------------------------------------------------------------
// K1: pack W into bf16 B-fragment layout (blocks 0..3) ∥ head4[]=-1 init.
//   Wpk entry (c*4+s)*64 + l holds 8 bf16 = W[k][16c+n], k=32s+8q+j, l=16q+n
//   head4: 4 chain heads per node (4-way lists cut walk critical path 4x).
// ---------------------------------------------------------------------------
__global__ __launch_bounds__(256)
void k1_pack_init(const float* __restrict__ W, short* __restrict__ Wpk,
                  int* __restrict__ head4)
{
    int bx = blockIdx.x;
    if (bx < 4) {
        int i = bx * 256 + threadIdx.x;   // 1024 entries
        if (i < 1024) {
            int l = i & 63, cs = i >> 6;
            int c = cs >> 2, s = cs & 3;
            int n = l & 15, q = l >> 4;
            short v[8];
            #pragma unroll
            for (int j = 0; j < 8; ++j)
                v[j] = f2bf(W[(32 * s + 8 * q + j) * HID + 16 * c + n]);
            *(bf16x8*)&Wpk[(size_t)i * 8] = *(const bf16x8*)v;
        }
    } else {
        int i4 = (bx - 4) * 256 + threadIdx.x;     // one int4 = one node's 4 heads
        if (i4 < N_NODES)
            ((int4*)head4)[i4] = make_int4(-1, -1, -1, -1);
    }
}

// ---------------------------------------------------------------------------
// K2: link (blocks 0..976) ∥ lin_att (rest) — FUSED.
// The score exp(tanh(...)) moved to aggregate, so link no longer reads
// p0/q1/q2 -> it is fully independent of the GEMM and runs concurrently
// under lin_att's ~85%-idle machine (R5's proven scan1 trick, bigger stakes).
//
// link: edge i -> chain slot i&3 of node e0:
//   old = atomicExch(&head4[e0*4 + (i&3)], i);  rec[i] = (e1, e2, next=old)
//   rec stores are sequential/coalesced int4.
//
// lin_att: unchanged v7 body (LDS-staged W, 8 A-loads, 16 MFMA).
//   A-frag: lane m=l&15, k=8*quad+j ; C/D: col=l&15, row=4*quad+reg [m89/m91]
// which==0 -> H0 fp32 + p0 ; which==1/2 -> H bf16 + q1/q2
// ---------------------------------------------------------------------------
__global__ __launch_bounds__(256)
void k2_lin_link(const float* __restrict__ feat0, const float* __restrict__ feat1,
                 const float* __restrict__ feat2,
                 const short* __restrict__ Wpk, const float* __restrict__ b_feat,
                 const float* __restrict__ W_att,
                 float* __restrict__ H0,
                 unsigned short* __restrict__ H1b, unsigned short* __restrict__ H2b,
                 float* __restrict__ p0, float* __restrict__ q1, float* __restrict__ q2,
                 const int* __restrict__ e0a, const int* __restrict__ e1a,
                 const int* __restrict__ e2a,
                 int* __restrict__ head4, int4* __restrict__ rec)
{
    __shared__ short Wlds[8192];   // 16 KB (lin branch only)

    const int bx = blockIdx.x;
    const int t  = threadIdx.x;

    if (bx < LINK_BLOCKS) {
        // ---------------- link branch ----------------
        int i = bx * 256 + t;
        if (i < N_EDGES / 4) {
            int4 e0v = ((const int4*)e0a)[i];
            int4 e1v = ((const int4*)e1a)[i];
            int4 e2v = ((const int4*)e2a)[i];
            int base = i * 4;
            // edge (base+k) -> slot k; 4x less head contention than 1 list
            int old0 = atomicExch(&head4[e0v.x * 4 + 0], base + 0);
            int old1 = atomicExch(&head4[e0v.y * 4 + 1], base + 1);
            int old2 = atomicExch(&head4[e0v.z * 4 + 2], base + 2);
            int old3 = atomicExch(&head4[e0v.w * 4 + 3], base + 3);
            rec[base + 0] = make_int4(e1v.x, e2v.x, old0, 0);
            rec[base + 1] = make_int4(e1v.y, e2v.y, old1, 0);
            rec[base + 2] = make_int4(e1v.z, e2v.z, old2, 0);
            rec[base + 3] = make_int4(e1v.w, e2v.w, old3, 0);
        }
        return;
    }

    // ---------------- lin_att branch ----------------
    const int gb = bx - LINK_BLOCKS;            // 0 .. 3*GEMM_BLOCKS-1
    const int which = gb / GEMM_BLOCKS;
    const int gx    = gb % GEMM_BLOCKS;

    const float* feat = (which == 0) ? feat0 : (which == 1) ? feat1 : feat2;
    float* sOut = (which == 0) ? p0 : (which == 1) ? q1 : q2;
    unsigned short* Hb = (which == 1) ? H1b : H2b;

    const int wv = t >> 6;
    const int l  = t & 63;
    const int n  = l & 15;
    const int q  = l >> 4;
    const int rowBase = gx * 64 + wv * 16;

    const int gRow = rowBase + n;
    const int lr = (gRow < N_NODES) ? gRow : (N_NODES - 1);   // clamp loads

    // --- 8 independent A loads (only VMEM in the hot path) ---
    f32x4 X[8];
    {
        const float* ap = &feat[(size_t)lr * IN_F + 8 * q];
        #pragma unroll
        for (int ss = 0; ss < 4; ++ss) {
            X[2 * ss]     = *(const f32x4*)(ap + 32 * ss);
            X[2 * ss + 1] = *(const f32x4*)(ap + 32 * ss + 4);
        }
    }

    // --- stage W (16 KB) into LDS once per block ---
    #pragma unroll
    for (int it = 0; it < 4; ++it) {
        int idx = it * 256 + t;
        *(bf16x8*)&Wlds[idx * 8] = *(const bf16x8*)&Wpk[(size_t)idx * 8];
    }
    __syncthreads();

    f32x4 acc[4];
    #pragma unroll
    for (int c = 0; c < 4; ++c) {
        float bv = b_feat[16 * c + n];
        acc[c][0] = bv; acc[c][1] = bv; acc[c][2] = bv; acc[c][3] = bv;
    }

    #pragma unroll
    for (int ss = 0; ss < 4; ++ss) {
        f32x4 x0 = X[2 * ss];
        f32x4 x1 = X[2 * ss + 1];
        bf16x8 a;
        a[0] = f2bf(x0[0]); a[1] = f2bf(x0[1]); a[2] = f2bf(x0[2]); a[3] = f2bf(x0[3]);
        a[4] = f2bf(x1[0]); a[5] = f2bf(x1[1]); a[6] = f2bf(x1[2]); a[7] = f2bf(x1[3]);
        #pragma unroll
        for (int c = 0; c < 4; ++c) {
            bf16x8 bfr = *(const bf16x8*)&Wlds[((c * 4 + ss) * 64 + l) * 8];
            acc[c] = __builtin_amdgcn_mfma_f32_16x16x32_bf16(a, bfr, acc[c], 0, 0, 0);
        }
    }

    // epilogue: store H (+ fused attention scalar in fp32)
    float part[4] = {0.f, 0.f, 0.f, 0.f};
    #pragma unroll
    for (int c = 0; c < 4; ++c) {
        int col = 16 * c + n;
        float a0 = W_att[col], a1 = W_att[HID + col];
        float ae = (which == 0) ? (a0 + a1 * (1.0f / 3.0f)) : (a1 * (1.0f / 3.0f));
        #pragma unroll
        for (int r = 0; r < 4; ++r) {
            int row = rowBase + 4 * q + r;
            if (row < N_NODES) {
                if (which == 0) H0[(size_t)row * HID + col] = acc[c][r];
                else            Hb[(size_t)row * HID + col] = f2bfu(acc[c][r]);
            }
            part[r] = fmaf(acc[c][r], ae, part[r]);
        }
    }
    #pragma unroll
    for (int r = 0; r < 4; ++r) {
        float p = part[r];
        p += __shfl_xor(p, 1, 64);
        p += __shfl_xor(p, 2, 64);
        p += __shfl_xor(p, 4, 64);
        p += __shfl_xor(p, 8, 64);
        int row = rowBase + 4 * q + r;
        if (n == 0 && row < N_NODES) sOut[row] = p;
    }
}

// ---------------------------------------------------------------------------
// Aggregate (4-chain walk): 16 lanes/node, branch-free clamped loads.
// Per iteration: 4 independent rec loads + 8 q-gathers + 8 H-row gathers all
// in flight (vs 1 dependent load before) -> chase critical path cut ~4x.
// Scores computed here: x = p0[n]+q1[e1]+q2[e2]+b_att; w = exp(tanh(x))
// (softmax shift-invariance, tanh bounded -> exact without segment max).
// out[n] = bias + H0[n]/3 + (1/(3*sum w)) * sum w*(H1[e1]+H2[e2])
// ---------------------------------------------------------------------------
__global__ __launch_bounds__(256)
void aggregate_mc_kernel(const int* __restrict__ head4,
                         const int4* __restrict__ rec,
                         const float* __restrict__ H0,
                         const unsigned short* __restrict__ H1b,
                         const unsigned short* __restrict__ H2b,
                         const float* __restrict__ p0, const float* __restrict__ q1,
                         const float* __restrict__ q2, const float* __restrict__ b_att,
                         const float* __restrict__ bias,
                         float* __restrict__ out)
{
    int gid  = blockIdx.x * 256 + threadIdx.x;
    int node = gid >> 4;
    int sub  = gid & 15;
    if (node >= N_NODES) return;

    int4 h4 = ((const int4*)head4)[node];
    int j0 = h4.x, j1 = h4.y, j2 = h4.z, j3 = h4.w;
    const bool hasEdges = (j0 >= 0) || (j1 >= 0) || (j2 >= 0) || (j3 >= 0);

    float pn = p0[node] + b_att[0];

    float denom = 0.0f;
    float ax = 0.0f, ay = 0.0f, az = 0.0f, aw = 0.0f;

    // sign(AND) set only when ALL chains done
    while ((j0 & j1 & j2 & j3) >= 0) {
        bool a0 = j0 >= 0, a1 = j1 >= 0, a2 = j2 >= 0, a3 = j3 >= 0;
        // clamped, unconditional loads: inactive chains re-read rec[0] (L1-hot)
        int4 r0 = rec[a0 ? j0 : 0];
        int4 r1 = rec[a1 ? j1 : 0];
        int4 r2 = rec[a2 ? j2 : 0];
        int4 r3 = rec[a3 ? j3 : 0];

        float x0 = pn + q1[r0.x] + q2[r0.y];
        float x1 = pn + q1[r1.x] + q2[r1.y];
        float x2 = pn + q1[r2.x] + q2[r2.y];
        float x3 = pn + q1[r3.x] + q2[r3.y];

        u16x4 h10 = *(const u16x4*)&H1b[(size_t)r0.x * HID + 4 * sub];
        u16x4 h20 = *(const u16x4*)&H2b[(size_t)r0.y * HID + 4 * sub];
        u16x4 h11 = *(const u16x4*)&H1b[(size_t)r1.x * HID + 4 * sub];
        u16x4 h21 = *(const u16x4*)&H2b[(size_t)r1.y * HID + 4 * sub];
        u16x4 h12 = *(const u16x4*)&H1b[(size_t)r2.x * HID + 4 * sub];
        u16x4 h22 = *(const u16x4*)&H2b[(size_t)r2.y * HID + 4 * sub];
        u16x4 h13 = *(const u16x4*)&H1b[(size_t)r3.x * HID + 4 * sub];
        u16x4 h23 = *(const u16x4*)&H2b[(size_t)r3.y * HID + 4 * sub];

        float w0 = a0 ? __expf(tanhf(x0)) : 0.0f;
        float w1 = a1 ? __expf(tanhf(x1)) : 0.0f;
        float w2 = a2 ? __expf(tanhf(x2)) : 0.0f;
        float w3 = a3 ? __expf(tanhf(x3)) : 0.0f;

        denom += (w0 + w1) + (w2 + w3);
        ax = fmaf(w0, bf2f(h10.x) + bf2f(h20.x), ax);
        ay = fmaf(w0, bf2f(h10.y) + bf2f(h20.y), ay);
        az = fmaf(w0, bf2f(h10.z) + bf2f(h20.z), az);
        aw = fmaf(w0, bf2f(h10.w) + bf2f(h20.w), aw);
        ax = fmaf(w1, bf2f(h11.x) + bf2f(h21.x), ax);
        ay = fmaf(w1, bf2f(h11.y) + bf2f(h21.y), ay);
        az = fmaf(w1, bf2f(h11.z) + bf2f(h21.z), az);
        aw = fmaf(w1, bf2f(h11.w) + bf2f(h21.w), aw);
        ax = fmaf(w2, bf2f(h12.x) + bf2f(h22.x), ax);
        ay = fmaf(w2, bf2f(h12.y) + bf2f(h22.y), ay);
        az = fmaf(w2, bf2f(h12.z) + bf2f(h22.z), az);
        aw = fmaf(w2, bf2f(h12.w) + bf2f(h22.w), aw);
        ax = fmaf(w3, bf2f(h13.x) + bf2f(h23.x), ax);
        ay = fmaf(w3, bf2f(h13.y) + bf2f(h23.y), ay);
        az = fmaf(w3, bf2f(h13.z) + bf2f(h23.z), az);
        aw = fmaf(w3, bf2f(h13.w) + bf2f(h23.w), aw);

        j0 = a0 ? r0.z : -1;
        j1 = a1 ? r1.z : -1;
        j2 = a2 ? r2.z : -1;
        j3 = a3 ? r3.z : -1;
    }

    float4 h0 = *(const float4*)&H0[(size_t)node * HID + 4 * sub];
    float4 bv = *(const float4*)&bias[4 * sub];
    float third = hasEdges ? (1.0f / 3.0f) : 0.0f;
    float inv   = hasEdges ? 1.0f / (3.0f * denom) : 0.0f;

    float4 o;
    o.x = bv.x + third * h0.x + inv * ax;
    o.y = bv.y + third * h0.y + inv * ay;
    o.z = bv.z + third * h0.z + inv * az;
    o.w = bv.w + third * h0.w + inv * aw;
    *(float4*)&out[(size_t)node * HID + 4 * sub] = o;
}

// ---------------------------------------------------------------------------
extern "C" void kernel_launch(void* const* d_in, const int* in_sizes, int n_in,
                              void* d_out, int out_size, void* d_ws, size_t ws_size,
                              hipStream_t stream)
{
    const float* feat0  = (const float*)d_in[0];
    const float* feat1  = (const float*)d_in[1];
    const float* feat2  = (const float*)d_in[2];
    const int*   edge0  = (const int*)d_in[3];
    const int*   edge1  = (const int*)d_in[4];
    const int*   edge2  = (const int*)d_in[5];
    const float* W_feat = (const float*)d_in[6];
    const float* b_feat = (const float*)d_in[7];
    const float* W_att  = (const float*)d_in[8];
    const float* b_att  = (const float*)d_in[9];
    const float* bias   = (const float*)d_in[10];
    float* out = (float*)d_out;

    // workspace layout (16B-aligned chunks first)
    int4*   rec  = (int4*)d_ws;                            // 1M int4 = 16 MB
    short*  Wpk  = (short*)(rec + N_EDGES);                // 8192 shorts (16 KB)
    float*  H0   = (float*)(Wpk + 8192);                   // 6.4M floats
    unsigned short* H1b = (unsigned short*)(H0 + (size_t)N_NODES * HID); // 6.4M
    unsigned short* H2b = H1b + (size_t)N_NODES * HID;                   // 6.4M
    float*  p0   = (float*)(H2b + (size_t)N_NODES * HID);
    float*  q1   = p0 + N_NODES;
    float*  q2   = q1 + N_NODES;
    int*    head4 = (int*)(q2 + N_NODES);                  // 400K ints (1.6 MB)
    // total ~72 MB

    dim3 blk(256);

    // K1: pack_w (4 blocks) ∥ head4=-1 init (391 blocks)
    k1_pack_init<<<4 + (N_NODES + 255) / 256, blk, 0, stream>>>(
        W_feat, Wpk, head4);

    // K2: link (977 blocks) ∥ fused 3x GEMM + attention partials (4689 blocks)
    k2_lin_link<<<LINK_BLOCKS + 3 * GEMM_BLOCKS, blk, 0, stream>>>(
        feat0, feat1, feat2, Wpk, b_feat, W_att,
        H0, H1b, H2b, p0, q1, q2,
        edge0, edge1, edge2, head4, rec);

    // K3: 4-chain walk aggregation (scores computed in-walk)
    aggregate_mc_kernel<<<((size_t)N_NODES * 16 + 255) / 256, blk, 0, stream>>>(
        head4, rec, H0, H1b, H2b, p0, q1, q2, b_att, bias, out);
}